// Round 7
// baseline (1019.097 us; speedup 1.0000x reference)
//
#include <hip/hip_runtime.h>
#include <hip/hip_bf16.h>

typedef __attribute__((ext_vector_type(8))) short  bf16x8;
typedef __attribute__((ext_vector_type(4))) float  f32x4;

#define MTPW 4   // tiles per wave in msg_kernel
#define LOG2E  1.442695041f
#define LOG2E2 2.885390082f

__device__ __forceinline__ float rcp_(float v){ return __builtin_amdgcn_rcpf(v); }
__device__ __forceinline__ float exp2_(float v){ return __builtin_amdgcn_exp2f(v); }
__device__ __forceinline__ unsigned pk2(float lo, float hi){
    __hip_bfloat162 h = __float22bfloat162_rn(float2{lo, hi});
    return *(unsigned*)&h;
}
__device__ __forceinline__ float lo2f(unsigned u){ return __uint_as_float(u << 16); }
__device__ __forceinline__ float hi2f(unsigned u){ return __uint_as_float(u & 0xFFFF0000u); }

union U4 { bf16x8 v; unsigned u[4]; };

__device__ __forceinline__ bf16x8 ldw8(const float* __restrict__ p){
    const float4 a = *(const float4*)p;
    const float4 b = *(const float4*)(p + 4);
    U4 r;
    r.u[0] = pk2(a.x, a.y); r.u[1] = pk2(a.z, a.w);
    r.u[2] = pk2(b.x, b.y); r.u[3] = pk2(b.z, b.w);
    return r.v;
}
// scaled variant: fold log2e (sigm rows) / 2log2e (tanh rows) into weights
__device__ __forceinline__ bf16x8 ldw8s(const float* __restrict__ p, float s){
    const float4 a = *(const float4*)p;
    const float4 b = *(const float4*)(p + 4);
    U4 r;
    r.u[0] = pk2(a.x*s, a.y*s); r.u[1] = pk2(a.z*s, a.w*s);
    r.u[2] = pk2(b.x*s, b.y*s); r.u[3] = pk2(b.z*s, b.w*s);
    return r.v;
}
__device__ __forceinline__ bf16x8 ldihs(const float* __restrict__ wih,
                                        const float* __restrict__ bi,
                                        const float* __restrict__ bh,
                                        int row, int lq, float s){
    U4 r;
    r.u[0] = r.u[1] = r.u[2] = r.u[3] = 0u;
    if (lq == 0) {
        const float* p = wih + row * 6;
        r.u[0] = pk2(p[0]*s, p[1]*s);
        r.u[1] = pk2(p[2]*s, p[3]*s);
        r.u[2] = pk2(p[4]*s, p[5]*s);
        r.u[3] = pk2((bi[row] + bh[row])*s, 0.0f);
    }
    return r.v;
}

// Redistribute per-edge 32-vector from D layout (lane q: positions {4q..4q+3}
// as W0/W1 [lo], {16+4q..16+4q+3} as W2/W3 [hi]) to B-frag/e-major layout
// (lane q: positions {8q..8q+7}). Select lo/hi at the TARGET.
__device__ __forceinline__ void redist(unsigned W0, unsigned W1, unsigned W2, unsigned W3,
                                       int sa, int sb, bool lo, unsigned out[4]){
    const unsigned a0 = (unsigned)__shfl((int)W0, sa, 64);
    const unsigned a1 = (unsigned)__shfl((int)W1, sa, 64);
    const unsigned a2 = (unsigned)__shfl((int)W0, sb, 64);
    const unsigned a3 = (unsigned)__shfl((int)W1, sb, 64);
    const unsigned b0 = (unsigned)__shfl((int)W2, sa, 64);
    const unsigned b1 = (unsigned)__shfl((int)W3, sa, 64);
    const unsigned b2 = (unsigned)__shfl((int)W2, sb, 64);
    const unsigned b3 = (unsigned)__shfl((int)W3, sb, 64);
    out[0] = lo ? a0 : b0;
    out[1] = lo ? a1 : b1;
    out[2] = lo ? a2 : b2;
    out[3] = lo ? a3 : b3;
}

// ---------------- kernel 1: coor = relu(x@W1^T)@W2^T -> bf16 [N,32] ----------------
__global__ __launch_bounds__(256) void coor_kernel(
    const float* __restrict__ x, const float* __restrict__ w1,
    const float* __restrict__ w2, unsigned short* __restrict__ coorb, int N)
{
    __shared__ float sW1[96];
    __shared__ float sW2[1024];
    const int tid = threadIdx.x;
    if (tid < 96) sW1[tid] = w1[tid];
    for (int i = tid; i < 1024; i += 256) sW2[i] = w2[i];
    __syncthreads();
    int n = blockIdx.x * 256 + tid;
    if (n >= N) return;
    const float x0 = x[n*3+0], x1 = x[n*3+1], x2 = x[n*3+2];
    float h[32];
#pragma unroll
    for (int k = 0; k < 32; ++k)
        h[k] = fmaxf(sW1[k*3+0]*x0 + sW1[k*3+1]*x1 + sW1[k*3+2]*x2, 0.0f);
    union { uint4 q[4]; unsigned u[16]; } st;
#pragma unroll
    for (int p = 0; p < 16; ++p) {
        float a0 = 0.f, a1 = 0.f;
#pragma unroll
        for (int k = 0; k < 32; ++k) {
            a0 += sW2[(2*p)  *32 + k] * h[k];
            a1 += sW2[(2*p+1)*32 + k] * h[k];
        }
        st.u[p] = pk2(a0, a1);
    }
    uint4* cp = (uint4*)(coorb + (size_t)n * 32);
#pragma unroll
    for (int w = 0; w < 4; ++w) cp[w] = st.q[w];
}

// ---------------- kernel 2: one-direction LSTM, 2 tiles (32 edges) per wave ----------------
// DIR=0: c_fwd -> cbuf (bf16 e-major). DIR=1: c_bwd; blend tr = 0.5*(cf+cb) in place.
// Weights carry folded log2e scales; gates use exp2/rcp forms that are inf-safe.
template<int DIR>
__global__ __launch_bounds__(256, 2) void lstm_kernel(
    const float* __restrict__ edge_traj,
    const float* __restrict__ w_ih, const float* __restrict__ w_hh,
    const float* __restrict__ b_ih, const float* __restrict__ b_hh,
    unsigned* __restrict__ cbuf, int E)
{
    const int lane = threadIdx.x & 63;
    const int wid  = threadIdx.x >> 6;
    const int le   = lane & 15;
    const int lq   = lane >> 4;
    const int sa   = ((lq & 1) << 5) + le;
    const int sb   = sa + 16;
    const bool lo  = (lq < 2);
    const bool l0  = (lq == 0);
    const f32x4 Z4 = {0.f, 0.f, 0.f, 0.f};

    bf16x8 wh[8], wx[8];
#pragma unroll
    for (int m = 0; m < 8; ++m) {
        const int row = 16*m + le;
        const float s = (m == 4 || m == 5) ? LOG2E2 : LOG2E;   // g-gate rows: tanh scale
        wh[m] = ldw8s(w_hh + row*32 + 8*lq, s);
        wx[m] = ldihs(w_ih, b_ih, b_hh, row, lq, s);
    }

    const long tp  = (long)blockIdx.x * 4 + wid;   // tile-pair index
    const long eb0 = tp * 32;
    if (eb0 >= E) return;

    const float* xb[2];
    bool vst[2];
#pragma unroll
    for (int p = 0; p < 2; ++p) {
        const long er = eb0 + p*16 + le;
        const long ec = (er < E) ? er : (E - 1);
        xb[p] = edge_traj + ec * 48;
        vst[p] = (er < E);
    }

    U4 hf[2];
    float cl[2][4], ch[2][4];
#pragma unroll
    for (int p = 0; p < 2; ++p) {
        hf[p].u[0] = hf[p].u[1] = hf[p].u[2] = hf[p].u[3] = 0u;
#pragma unroll
        for (int r = 0; r < 4; ++r) { cl[p][r] = 0.f; ch[p][r] = 0.f; }
    }

#pragma unroll
    for (int t = 0; t < 8; ++t) {
        const int te = DIR ? (7 - t) : t;
        U4 xf[2];
#pragma unroll
        for (int p = 0; p < 2; ++p) {
            const float* xp = xb[p] + te * 6;
            const float2 a  = *(const float2*)xp;
            const float2 b2 = *(const float2*)(xp + 2);
            const float2 c2 = *(const float2*)(xp + 4);
            xf[p].u[0] = l0 ? pk2(a.x, a.y)   : 0u;
            xf[p].u[1] = l0 ? pk2(b2.x, b2.y) : 0u;
            xf[p].u[2] = l0 ? pk2(c2.x, c2.y) : 0u;
            xf[p].u[3] = l0 ? 0x3f80u         : 0u;   // bias slot = 1.0
        }
        f32x4 acc[2][8];
#pragma unroll
        for (int p = 0; p < 2; ++p)
#pragma unroll
            for (int m = 0; m < 8; ++m)
                acc[p][m] = __builtin_amdgcn_mfma_f32_16x16x32_bf16(wx[m], xf[p].v, Z4, 0, 0, 0);
        if (t > 0) {
#pragma unroll
            for (int p = 0; p < 2; ++p)
#pragma unroll
                for (int m = 0; m < 8; ++m)
                    acc[p][m] = __builtin_amdgcn_mfma_f32_16x16x32_bf16(wh[m], hf[p].v, acc[p][m], 0, 0, 0);
        }
#pragma unroll
        for (int p = 0; p < 2; ++p) {
            float h_lo[4], h_hi[4];
#pragma unroll
            for (int r = 0; r < 4; ++r) {
                // lo half (units 4q+r)
                float ig = rcp_(1.0f + exp2_(-acc[p][0][r]));
                float fg = rcp_(1.0f + exp2_(-acc[p][2][r]));
                float gg = 1.0f - 2.0f * rcp_(exp2_(acc[p][4][r]) + 1.0f);
                float og = rcp_(1.0f + exp2_(-acc[p][6][r]));
                cl[p][r] = fg * cl[p][r] + ig * gg;
                h_lo[r]  = og * (1.0f - 2.0f * rcp_(exp2_(LOG2E2 * cl[p][r]) + 1.0f));
                // hi half (units 16+4q+r)
                ig = rcp_(1.0f + exp2_(-acc[p][1][r]));
                fg = rcp_(1.0f + exp2_(-acc[p][3][r]));
                gg = 1.0f - 2.0f * rcp_(exp2_(acc[p][5][r]) + 1.0f);
                og = rcp_(1.0f + exp2_(-acc[p][7][r]));
                ch[p][r] = fg * ch[p][r] + ig * gg;
                h_hi[r]  = og * (1.0f - 2.0f * rcp_(exp2_(LOG2E2 * ch[p][r]) + 1.0f));
            }
            if (t < 7)
                redist(pk2(h_lo[0], h_lo[1]), pk2(h_lo[2], h_lo[3]),
                       pk2(h_hi[0], h_hi[1]), pk2(h_hi[2], h_hi[3]),
                       sa, sb, lo, hf[p].u);
        }
    }

    // c -> e-major bf16 (B-frag layout for downstream MFMA)
#pragma unroll
    for (int p = 0; p < 2; ++p) {
        U4 cw;
        redist(pk2(cl[p][0], cl[p][1]), pk2(cl[p][2], cl[p][3]),
               pk2(ch[p][0], ch[p][1]), pk2(ch[p][2], ch[p][3]),
               sa, sb, lo, cw.u);
        if (vst[p]) {
            unsigned* dp = cbuf + (eb0 + p*16 + le) * 16 + lq * 4;
            if (DIR == 0) {
                *(uint4*)dp = *(uint4*)cw.u;
            } else {
                const uint4 f = *(const uint4*)dp;
                uint4 o;
                o.x = pk2(0.5f*(lo2f(f.x)+lo2f(cw.u[0])), 0.5f*(hi2f(f.x)+hi2f(cw.u[0])));
                o.y = pk2(0.5f*(lo2f(f.y)+lo2f(cw.u[1])), 0.5f*(hi2f(f.y)+hi2f(cw.u[1])));
                o.z = pk2(0.5f*(lo2f(f.z)+lo2f(cw.u[2])), 0.5f*(hi2f(f.z)+hi2f(cw.u[2])));
                o.w = pk2(0.5f*(lo2f(f.w)+lo2f(cw.u[3])), 0.5f*(hi2f(f.w)+hi2f(cw.u[3])));
                *(uint4*)dp = o;
            }
        }
    }
}

// ---------------- kernel 3: message MLP + scatter ----------------
__global__ __launch_bounds__(256, 4) void msg_kernel(
    const unsigned* __restrict__ tr,      // [E][16] words, e-major bf16
    const float* __restrict__ nn2_w1, const float* __restrict__ nn2_w2,
    const int* __restrict__ edge_index,
    const unsigned short* __restrict__ coorb,
    float* __restrict__ agg, int E)
{
    const int lane = threadIdx.x & 63;
    const int wid  = threadIdx.x >> 6;
    const int le   = lane & 15;
    const int lq   = lane >> 4;
    const int sa   = ((lq & 1) << 5) + le;
    const int sb   = sa + 16;
    const bool lo  = (lq < 2);
    const f32x4 Z4 = {0.f, 0.f, 0.f, 0.f};

    bf16x8 w1a[2][3], w2a[2];
#pragma unroll
    for (int mm = 0; mm < 2; ++mm) {
        const int row = 16*mm + le;
#pragma unroll
        for (int kc = 0; kc < 3; ++kc)
            w1a[mm][kc] = ldw8(nn2_w1 + row*96 + 32*kc + 8*lq);
        w2a[mm] = ldw8(nn2_w2 + row*32 + 8*lq);
    }

    const long gw = (long)blockIdx.x * 4 + wid;
    for (int it = 0; it < MTPW; ++it) {
        const long tile = gw * MTPW + it;
        const long e0 = tile * 16;
        if (e0 >= E) break;
        const long e_raw = e0 + le;
        const bool valid = e_raw < E;
        const long ec = valid ? e_raw : (E - 1);

        U4 tf;
        *(uint4*)tf.u = *(const uint4*)(tr + ec * 16 + lq * 4);

        const int src = edge_index[ec];
        const int dst = edge_index[E + ec];
        U4 df, sf;
        {
            const uint4 dv = *(const uint4*)(coorb + (size_t)dst*32 + lq*8);
            const uint4 sv = *(const uint4*)(coorb + (size_t)src*32 + lq*8);
            df.u[0]=dv.x; df.u[1]=dv.y; df.u[2]=dv.z; df.u[3]=dv.w;
            sf.u[0]=sv.x; sf.u[1]=sv.y; sf.u[2]=sv.z; sf.u[3]=sv.w;
        }

        f32x4 h1[2];
#pragma unroll
        for (int mm = 0; mm < 2; ++mm) {
            f32x4 a = __builtin_amdgcn_mfma_f32_16x16x32_bf16(w1a[mm][0], df.v, Z4, 0, 0, 0);
            a = __builtin_amdgcn_mfma_f32_16x16x32_bf16(w1a[mm][1], sf.v, a, 0, 0, 0);
            a = __builtin_amdgcn_mfma_f32_16x16x32_bf16(w1a[mm][2], tf.v, a, 0, 0, 0);
            h1[mm] = a;
        }
        U4 gf;
        redist(pk2(fmaxf(h1[0][0],0.f), fmaxf(h1[0][1],0.f)),
               pk2(fmaxf(h1[0][2],0.f), fmaxf(h1[0][3],0.f)),
               pk2(fmaxf(h1[1][0],0.f), fmaxf(h1[1][1],0.f)),
               pk2(fmaxf(h1[1][2],0.f), fmaxf(h1[1][3],0.f)),
               sa, sb, lo, gf.u);

#pragma unroll
        for (int mm = 0; mm < 2; ++mm) {
            const f32x4 o = __builtin_amdgcn_mfma_f32_16x16x32_bf16(w2a[mm], gf.v, Z4, 0, 0, 0);
            if (valid) {
#pragma unroll
                for (int r = 0; r < 4; ++r)
                    atomicAdd(agg + (size_t)dst*32 + (16*mm + 4*lq + r), o[r]);
            }
        }
    }
}

// ---------------- kernel 4: partials[b][k] = sum_{n in block b} relu(agg[n]@nn_w1^T)[k] ----------------
__global__ __launch_bounds__(256) void agg_kernel(
    const float* __restrict__ agg, const float* __restrict__ nn_w1,
    float* __restrict__ partials, int N)
{
    __shared__ float sW[1024];
    __shared__ float sP[4][32];
    const int tid = threadIdx.x;
    for (int i = tid; i < 1024; i += 256) sW[i] = nn_w1[i];
    __syncthreads();
    const int n = blockIdx.x*256 + tid;
    float h[32];
    if (n < N) {
        float a[32];
        const float4* ap = (const float4*)(agg + (size_t)n*32);
#pragma unroll
        for (int k4 = 0; k4 < 8; ++k4) {
            const float4 v = ap[k4];
            a[k4*4]=v.x; a[k4*4+1]=v.y; a[k4*4+2]=v.z; a[k4*4+3]=v.w;
        }
#pragma unroll
        for (int jj = 0; jj < 32; ++jj) {
            float acc = 0.f;
#pragma unroll
            for (int k = 0; k < 32; ++k) acc += sW[jj*32+k]*a[k];
            h[jj] = fmaxf(acc, 0.f);
        }
    } else {
#pragma unroll
        for (int jj = 0; jj < 32; ++jj) h[jj] = 0.f;
    }
#pragma unroll
    for (int m = 1; m < 64; m <<= 1) {
#pragma unroll
        for (int k = 0; k < 32; ++k) h[k] += __shfl_xor(h[k], m, 64);
    }
    if ((tid & 63) == 0) {
#pragma unroll
        for (int k = 0; k < 32; ++k) sP[tid >> 6][k] = h[k];
    }
    __syncthreads();
    if (tid < 32)
        partials[(size_t)blockIdx.x * 32 + tid]
            = sP[0][tid] + sP[1][tid] + sP[2][tid] + sP[3][tid];
}

// ---------------- kernel 5: s32 = sum(partials); out = nn_w2 @ s32 ----------------
__global__ __launch_bounds__(256) void reduce_kernel(
    const float* __restrict__ partials, const float* __restrict__ nn_w2,
    float* __restrict__ out, int nblk)
{
    __shared__ float sR[8][32];
    __shared__ float sS[32];
    const int tid = threadIdx.x;
    const int col = tid & 31;
    const int row = tid >> 5;          // 8 rows
    float s = 0.f;
    for (int i = row; i < nblk; i += 8) s += partials[(size_t)i*32 + col];
    sR[row][col] = s;
    __syncthreads();
    if (row == 0) {
        float t = 0.f;
#pragma unroll
        for (int r = 0; r < 8; ++r) t += sR[r][col];
        sS[col] = t;
    }
    __syncthreads();
    if (tid < 64) {
        float acc = 0.f;
#pragma unroll
        for (int k = 0; k < 32; ++k) acc += nn_w2[tid*32+k] * sS[k];
        out[tid] = acc;
    }
}

extern "C" void kernel_launch(void* const* d_in, const int* in_sizes, int n_in,
                              void* d_out, int out_size, void* d_ws, size_t ws_size,
                              hipStream_t stream)
{
    const float* x         = (const float*)d_in[0];
    const float* edge_traj = (const float*)d_in[1];
    const float* w_ih_f    = (const float*)d_in[2];
    const float* w_hh_f    = (const float*)d_in[3];
    const float* b_ih_f    = (const float*)d_in[4];
    const float* b_hh_f    = (const float*)d_in[5];
    const float* w_ih_b    = (const float*)d_in[6];
    const float* w_hh_b    = (const float*)d_in[7];
    const float* b_ih_b    = (const float*)d_in[8];
    const float* b_hh_b    = (const float*)d_in[9];
    const float* coor_w1   = (const float*)d_in[10];
    const float* coor_w2   = (const float*)d_in[11];
    const float* nn2_w1    = (const float*)d_in[12];
    const float* nn2_w2    = (const float*)d_in[13];
    const float* nn_w1     = (const float*)d_in[14];
    const float* nn_w2     = (const float*)d_in[15];
    const int* edge_index  = (const int*)d_in[16];
    const int N = in_sizes[0] / 3;
    const int E = in_sizes[16] / 2;
    const int nblk = (N + 255) / 256;

    float* agg = (float*)d_ws;                                   // N*32 f32
    float* partials = agg + (size_t)N * 32;                      // nblk*32 f32
    unsigned short* coorb = (unsigned short*)(partials + (size_t)nblk * 32); // N*32 bf16
    unsigned* cbuf = (unsigned*)(coorb + (size_t)N * 32);        // E*16 u32

    (void)hipMemsetAsync(agg, 0, (size_t)N * 32 * sizeof(float), stream);

    coor_kernel<<<nblk, 256, 0, stream>>>(x, coor_w1, coor_w2, coorb, N);

    const long tiles   = ((long)E + 15) / 16;
    const long pairs   = (tiles + 1) / 2;
    const int  lblocks = (int)((pairs + 3) / 4);
    lstm_kernel<0><<<lblocks, 256, 0, stream>>>(edge_traj,
        w_ih_f, w_hh_f, b_ih_f, b_hh_f, cbuf, E);
    lstm_kernel<1><<<lblocks, 256, 0, stream>>>(edge_traj,
        w_ih_b, w_hh_b, b_ih_b, b_hh_b, cbuf, E);

    const int mblocks = (int)((tiles + 4*MTPW - 1) / (4*MTPW));
    msg_kernel<<<mblocks, 256, 0, stream>>>(cbuf, nn2_w1, nn2_w2,
        edge_index, coorb, agg, E);

    agg_kernel<<<nblk, 256, 0, stream>>>(agg, nn_w1, partials, N);
    reduce_kernel<<<1, 256, 0, stream>>>(partials, nn_w2, (float*)d_out, nblk);
}

// Round 8
// 893.941 us; speedup vs baseline: 1.1400x; 1.1400x over previous
//
#include <hip/hip_runtime.h>
#include <hip/hip_bf16.h>

typedef __attribute__((ext_vector_type(8))) short  bf16x8;
typedef __attribute__((ext_vector_type(4))) float  f32x4;

#define MTPW 4   // tiles per wave in msg_kernel
#define LOG2E  1.442695041f
#define LOG2E2 2.885390082f

__device__ __forceinline__ float rcp_(float v){ return __builtin_amdgcn_rcpf(v); }
__device__ __forceinline__ float exp2_(float v){ return __builtin_amdgcn_exp2f(v); }
__device__ __forceinline__ unsigned pk2(float lo, float hi){
    __hip_bfloat162 h = __float22bfloat162_rn(float2{lo, hi});
    return *(unsigned*)&h;
}
__device__ __forceinline__ float lo2f(unsigned u){ return __uint_as_float(u << 16); }
__device__ __forceinline__ float hi2f(unsigned u){ return __uint_as_float(u & 0xFFFF0000u); }

union U4 { bf16x8 v; unsigned u[4]; };

// identity-order 8-column loader (coor chunks: slot k = unit k)
__device__ __forceinline__ bf16x8 ldw8(const float* __restrict__ p){
    const float4 a = *(const float4*)p;
    const float4 b = *(const float4*)(p + 4);
    U4 r;
    r.u[0] = pk2(a.x, a.y); r.u[1] = pk2(a.z, a.w);
    r.u[2] = pk2(b.x, b.y); r.u[3] = pk2(b.z, b.w);
    return r.v;
}
// sigma-permuted loader: slot 8q+j <- column sigma(8q+j) = {4q+j (j<4), 16+4q+j-4}
// rowp points at the row's column-0; scale s folded into bf16.
__device__ __forceinline__ bf16x8 ldw8p(const float* __restrict__ rowp, int lq, float s){
    const float4 a = *(const float4*)(rowp + 4*lq);
    const float4 b = *(const float4*)(rowp + 16 + 4*lq);
    U4 r;
    r.u[0] = pk2(a.x*s, a.y*s); r.u[1] = pk2(a.z*s, a.w*s);
    r.u[2] = pk2(b.x*s, b.y*s); r.u[3] = pk2(b.z*s, b.w*s);
    return r.v;
}
// [Wih | bias | 0] A-fragment (x-MFMA, identity k): lanes lq>0 zero
__device__ __forceinline__ bf16x8 ldihs(const float* __restrict__ wih,
                                        const float* __restrict__ bi,
                                        const float* __restrict__ bh,
                                        int row, int lq, float s){
    U4 r;
    r.u[0] = r.u[1] = r.u[2] = r.u[3] = 0u;
    if (lq == 0) {
        const float* p = wih + row * 6;
        r.u[0] = pk2(p[0]*s, p[1]*s);
        r.u[1] = pk2(p[2]*s, p[3]*s);
        r.u[2] = pk2(p[4]*s, p[5]*s);
        r.u[3] = pk2((bi[row] + bh[row])*s, 0.0f);
    }
    return r.v;
}

// ---------------- kernel 1: coor = relu(x@W1^T)@W2^T -> bf16 [N,32] ----------------
__global__ __launch_bounds__(256) void coor_kernel(
    const float* __restrict__ x, const float* __restrict__ w1,
    const float* __restrict__ w2, unsigned short* __restrict__ coorb, int N)
{
    __shared__ float sW1[96];
    __shared__ float sW2[1024];
    const int tid = threadIdx.x;
    if (tid < 96) sW1[tid] = w1[tid];
    for (int i = tid; i < 1024; i += 256) sW2[i] = w2[i];
    __syncthreads();
    int n = blockIdx.x * 256 + tid;
    if (n >= N) return;
    const float x0 = x[n*3+0], x1 = x[n*3+1], x2 = x[n*3+2];
    float h[32];
#pragma unroll
    for (int k = 0; k < 32; ++k)
        h[k] = fmaxf(sW1[k*3+0]*x0 + sW1[k*3+1]*x1 + sW1[k*3+2]*x2, 0.0f);
    union { uint4 q[4]; unsigned u[16]; } st;
#pragma unroll
    for (int p = 0; p < 16; ++p) {
        float a0 = 0.f, a1 = 0.f;
#pragma unroll
        for (int k = 0; k < 32; ++k) {
            a0 += sW2[(2*p)  *32 + k] * h[k];
            a1 += sW2[(2*p+1)*32 + k] * h[k];
        }
        st.u[p] = pk2(a0, a1);
    }
    uint4* cp = (uint4*)(coorb + (size_t)n * 32);
#pragma unroll
    for (int w = 0; w < 4; ++w) cp[w] = st.q[w];
}

// ---------------- kernel 2: one-direction LSTM, 1 tile (16 edges) per wave ----------------
// Whh columns sigma-permuted so the gate output packs DIRECTLY into the next
// step's B-fragment: zero cross-lane ops in the recurrence.
// Weight scales fold the exp2 conversion: i,f,o rows * -log2e; g rows * 2log2e.
// Gates use merged-rcp algebra: 5 exp2 + 2 rcp per unit-step.
// cbuf is written in sigma-layout e-major; msg_kernel compensates via permuted
// nn2_w1 traj-chunk columns.
template<int DIR>
__global__ __launch_bounds__(256, 3) void lstm_kernel(
    const float* __restrict__ edge_traj,
    const float* __restrict__ w_ih, const float* __restrict__ w_hh,
    const float* __restrict__ b_ih, const float* __restrict__ b_hh,
    unsigned* __restrict__ cbuf, int E)
{
    const int lane = threadIdx.x & 63;
    const int wid  = threadIdx.x >> 6;
    const int le   = lane & 15;
    const int lq   = lane >> 4;
    const bool l0  = (lq == 0);
    const f32x4 Z4 = {0.f, 0.f, 0.f, 0.f};

    bf16x8 wh[8], wx[8];
#pragma unroll
    for (int m = 0; m < 8; ++m) {
        const int row = 16*m + le;
        const float s = (m == 4 || m == 5) ? LOG2E2 : -LOG2E;
        wh[m] = ldw8p(w_hh + row*32, lq, s);
        wx[m] = ldihs(w_ih, b_ih, b_hh, row, lq, s);
    }

    const long tile = (long)blockIdx.x * 4 + wid;
    const long e0 = tile * 16;
    if (e0 >= E) return;
    const long er = e0 + le;
    const bool valid = er < E;
    const long ec = valid ? er : (E - 1);
    const float* xb = edge_traj + ec * 48;

    U4 hf; hf.u[0] = hf.u[1] = hf.u[2] = hf.u[3] = 0u;
    float cl[4] = {0,0,0,0}, ch[4] = {0,0,0,0};
#pragma unroll
    for (int t = 0; t < 8; ++t) {
        const int te = DIR ? (7 - t) : t;
        U4 xf;
        {
            const float* xp = xb + te * 6;
            const float2 a  = *(const float2*)xp;
            const float2 b2 = *(const float2*)(xp + 2);
            const float2 c2 = *(const float2*)(xp + 4);
            xf.u[0] = l0 ? pk2(a.x, a.y)   : 0u;
            xf.u[1] = l0 ? pk2(b2.x, b2.y) : 0u;
            xf.u[2] = l0 ? pk2(c2.x, c2.y) : 0u;
            xf.u[3] = l0 ? 0x3f80u         : 0u;   // bias slot = 1.0
        }
        f32x4 acc[8];
#pragma unroll
        for (int m = 0; m < 8; ++m)
            acc[m] = __builtin_amdgcn_mfma_f32_16x16x32_bf16(wx[m], xf.v, Z4, 0, 0, 0);
        if (t > 0) {
#pragma unroll
            for (int m = 0; m < 8; ++m)
                acc[m] = __builtin_amdgcn_mfma_f32_16x16x32_bf16(wh[m], hf.v, acc[m], 0, 0, 0);
        }
        float h_lo[4], h_hi[4];
#pragma unroll
        for (int r = 0; r < 4; ++r) {
            // lo half (units 4q+r): Ea=e^-i, Ef=e^-f, Eg=e^2g, Eo=e^-o
            {
                const float Ea = exp2_(acc[0][r]);
                const float Ef = exp2_(acc[2][r]);
                const float Eg = exp2_(acc[4][r]);
                const float Eo = exp2_(acc[6][r]);
                const float p  = (Ea + 1.f) * (Eg + 1.f);
                const float f1 = Ef + 1.f;
                const float num = fmaf(cl[r], p, (Eg - 1.f) * f1);
                cl[r] = num * rcp_(p * f1);
                const float Ec = exp2_(LOG2E2 * cl[r]);
                h_lo[r] = (Ec - 1.f) * rcp_((Eo + 1.f) * (Ec + 1.f));
            }
            // hi half (units 16+4q+r)
            {
                const float Ea = exp2_(acc[1][r]);
                const float Ef = exp2_(acc[3][r]);
                const float Eg = exp2_(acc[5][r]);
                const float Eo = exp2_(acc[7][r]);
                const float p  = (Ea + 1.f) * (Eg + 1.f);
                const float f1 = Ef + 1.f;
                const float num = fmaf(ch[r], p, (Eg - 1.f) * f1);
                ch[r] = num * rcp_(p * f1);
                const float Ec = exp2_(LOG2E2 * ch[r]);
                h_hi[r] = (Ec - 1.f) * rcp_((Eo + 1.f) * (Ec + 1.f));
            }
        }
        if (t < 7) {
            hf.u[0] = pk2(h_lo[0], h_lo[1]);
            hf.u[1] = pk2(h_lo[2], h_lo[3]);
            hf.u[2] = pk2(h_hi[0], h_hi[1]);
            hf.u[3] = pk2(h_hi[2], h_hi[3]);
        }
    }

    // c -> sigma-layout e-major bf16 (words 4q+w of edge er)
    if (valid) {
        U4 cw;
        cw.u[0] = pk2(cl[0], cl[1]);
        cw.u[1] = pk2(cl[2], cl[3]);
        cw.u[2] = pk2(ch[0], ch[1]);
        cw.u[3] = pk2(ch[2], ch[3]);
        unsigned* dp = cbuf + er * 16 + lq * 4;
        if (DIR == 0) {
            *(uint4*)dp = *(uint4*)cw.u;
        } else {
            const uint4 f = *(const uint4*)dp;
            uint4 o;
            o.x = pk2(0.5f*(lo2f(f.x)+lo2f(cw.u[0])), 0.5f*(hi2f(f.x)+hi2f(cw.u[0])));
            o.y = pk2(0.5f*(lo2f(f.y)+lo2f(cw.u[1])), 0.5f*(hi2f(f.y)+hi2f(cw.u[1])));
            o.z = pk2(0.5f*(lo2f(f.z)+lo2f(cw.u[2])), 0.5f*(hi2f(f.z)+hi2f(cw.u[2])));
            o.w = pk2(0.5f*(lo2f(f.w)+lo2f(cw.u[3])), 0.5f*(hi2f(f.w)+hi2f(cw.u[3])));
            *(uint4*)dp = o;
        }
    }
}

// ---------------- kernel 3: message MLP + scatter ----------------
// tr is sigma-layout -> w1a traj chunk uses permuted columns; hidden layer
// packs D-layout directly -> w2a uses permuted columns. No cross-lane ops.
__global__ __launch_bounds__(256, 4) void msg_kernel(
    const unsigned* __restrict__ tr,      // [E][16] words, sigma-layout bf16
    const float* __restrict__ nn2_w1, const float* __restrict__ nn2_w2,
    const int* __restrict__ edge_index,
    const unsigned short* __restrict__ coorb,
    float* __restrict__ agg, int E)
{
    const int lane = threadIdx.x & 63;
    const int wid  = threadIdx.x >> 6;
    const int le   = lane & 15;
    const int lq   = lane >> 4;
    const f32x4 Z4 = {0.f, 0.f, 0.f, 0.f};

    bf16x8 w1a[2][3], w2a[2];
#pragma unroll
    for (int mm = 0; mm < 2; ++mm) {
        const int row = 16*mm + le;
        w1a[mm][0] = ldw8(nn2_w1 + row*96 +  8*lq);          // coor_dst (identity)
        w1a[mm][1] = ldw8(nn2_w1 + row*96 + 32 + 8*lq);      // coor_src (identity)
        w1a[mm][2] = ldw8p(nn2_w1 + row*96 + 64, lq, 1.0f);  // traj (sigma)
        w2a[mm]    = ldw8p(nn2_w2 + row*32, lq, 1.0f);       // hidden (sigma)
    }

    const long gw = (long)blockIdx.x * 4 + wid;
    for (int it = 0; it < MTPW; ++it) {
        const long tile = gw * MTPW + it;
        const long e0 = tile * 16;
        if (e0 >= E) break;
        const long e_raw = e0 + le;
        const bool valid = e_raw < E;
        const long ec = valid ? e_raw : (E - 1);

        U4 tf;
        *(uint4*)tf.u = *(const uint4*)(tr + ec * 16 + lq * 4);

        const int src = edge_index[ec];
        const int dst = edge_index[E + ec];
        U4 df, sf;
        {
            const uint4 dv = *(const uint4*)(coorb + (size_t)dst*32 + lq*8);
            const uint4 sv = *(const uint4*)(coorb + (size_t)src*32 + lq*8);
            df.u[0]=dv.x; df.u[1]=dv.y; df.u[2]=dv.z; df.u[3]=dv.w;
            sf.u[0]=sv.x; sf.u[1]=sv.y; sf.u[2]=sv.z; sf.u[3]=sv.w;
        }

        f32x4 h1[2];
#pragma unroll
        for (int mm = 0; mm < 2; ++mm) {
            f32x4 a = __builtin_amdgcn_mfma_f32_16x16x32_bf16(w1a[mm][0], df.v, Z4, 0, 0, 0);
            a = __builtin_amdgcn_mfma_f32_16x16x32_bf16(w1a[mm][1], sf.v, a, 0, 0, 0);
            a = __builtin_amdgcn_mfma_f32_16x16x32_bf16(w1a[mm][2], tf.v, a, 0, 0, 0);
            h1[mm] = a;
        }
        // hidden D-layout: lane q holds units {4q+r (mm=0), 16+4q+r (mm=1)} -> direct sigma pack
        U4 gf;
        gf.u[0] = pk2(fmaxf(h1[0][0],0.f), fmaxf(h1[0][1],0.f));
        gf.u[1] = pk2(fmaxf(h1[0][2],0.f), fmaxf(h1[0][3],0.f));
        gf.u[2] = pk2(fmaxf(h1[1][0],0.f), fmaxf(h1[1][1],0.f));
        gf.u[3] = pk2(fmaxf(h1[1][2],0.f), fmaxf(h1[1][3],0.f));

#pragma unroll
        for (int mm = 0; mm < 2; ++mm) {
            const f32x4 o = __builtin_amdgcn_mfma_f32_16x16x32_bf16(w2a[mm], gf.v, Z4, 0, 0, 0);
            if (valid) {
#pragma unroll
                for (int r = 0; r < 4; ++r)
                    atomicAdd(agg + (size_t)dst*32 + (16*mm + 4*lq + r), o[r]);
            }
        }
    }
}

// ---------------- kernel 4: partials[b][k] = sum_{n in block b} relu(agg[n]@nn_w1^T)[k] ----------------
__global__ __launch_bounds__(256) void agg_kernel(
    const float* __restrict__ agg, const float* __restrict__ nn_w1,
    float* __restrict__ partials, int N)
{
    __shared__ float sW[1024];
    __shared__ float sP[4][32];
    const int tid = threadIdx.x;
    for (int i = tid; i < 1024; i += 256) sW[i] = nn_w1[i];
    __syncthreads();
    const int n = blockIdx.x*256 + tid;
    float h[32];
    if (n < N) {
        float a[32];
        const float4* ap = (const float4*)(agg + (size_t)n*32);
#pragma unroll
        for (int k4 = 0; k4 < 8; ++k4) {
            const float4 v = ap[k4];
            a[k4*4]=v.x; a[k4*4+1]=v.y; a[k4*4+2]=v.z; a[k4*4+3]=v.w;
        }
#pragma unroll
        for (int jj = 0; jj < 32; ++jj) {
            float acc = 0.f;
#pragma unroll
            for (int k = 0; k < 32; ++k) acc += sW[jj*32+k]*a[k];
            h[jj] = fmaxf(acc, 0.f);
        }
    } else {
#pragma unroll
        for (int jj = 0; jj < 32; ++jj) h[jj] = 0.f;
    }
#pragma unroll
    for (int m = 1; m < 64; m <<= 1) {
#pragma unroll
        for (int k = 0; k < 32; ++k) h[k] += __shfl_xor(h[k], m, 64);
    }
    if ((tid & 63) == 0) {
#pragma unroll
        for (int k = 0; k < 32; ++k) sP[tid >> 6][k] = h[k];
    }
    __syncthreads();
    if (tid < 32)
        partials[(size_t)blockIdx.x * 32 + tid]
            = sP[0][tid] + sP[1][tid] + sP[2][tid] + sP[3][tid];
}

// ---------------- kernel 5: s32 = sum(partials); out = nn_w2 @ s32 ----------------
__global__ __launch_bounds__(256) void reduce_kernel(
    const float* __restrict__ partials, const float* __restrict__ nn_w2,
    float* __restrict__ out, int nblk)
{
    __shared__ float sR[8][32];
    __shared__ float sS[32];
    const int tid = threadIdx.x;
    const int col = tid & 31;
    const int row = tid >> 5;          // 8 rows
    float s = 0.f;
    for (int i = row; i < nblk; i += 8) s += partials[(size_t)i*32 + col];
    sR[row][col] = s;
    __syncthreads();
    if (row == 0) {
        float t = 0.f;
#pragma unroll
        for (int r = 0; r < 8; ++r) t += sR[r][col];
        sS[col] = t;
    }
    __syncthreads();
    if (tid < 64) {
        float acc = 0.f;
#pragma unroll
        for (int k = 0; k < 32; ++k) acc += nn_w2[tid*32+k] * sS[k];
        out[tid] = acc;
    }
}

extern "C" void kernel_launch(void* const* d_in, const int* in_sizes, int n_in,
                              void* d_out, int out_size, void* d_ws, size_t ws_size,
                              hipStream_t stream)
{
    const float* x         = (const float*)d_in[0];
    const float* edge_traj = (const float*)d_in[1];
    const float* w_ih_f    = (const float*)d_in[2];
    const float* w_hh_f    = (const float*)d_in[3];
    const float* b_ih_f    = (const float*)d_in[4];
    const float* b_hh_f    = (const float*)d_in[5];
    const float* w_ih_b    = (const float*)d_in[6];
    const float* w_hh_b    = (const float*)d_in[7];
    const float* b_ih_b    = (const float*)d_in[8];
    const float* b_hh_b    = (const float*)d_in[9];
    const float* coor_w1   = (const float*)d_in[10];
    const float* coor_w2   = (const float*)d_in[11];
    const float* nn2_w1    = (const float*)d_in[12];
    const float* nn2_w2    = (const float*)d_in[13];
    const float* nn_w1     = (const float*)d_in[14];
    const float* nn_w2     = (const float*)d_in[15];
    const int* edge_index  = (const int*)d_in[16];
    const int N = in_sizes[0] / 3;
    const int E = in_sizes[16] / 2;
    const int nblk = (N + 255) / 256;

    float* agg = (float*)d_ws;                                   // N*32 f32
    float* partials = agg + (size_t)N * 32;                      // nblk*32 f32
    unsigned short* coorb = (unsigned short*)(partials + (size_t)nblk * 32); // N*32 bf16
    unsigned* cbuf = (unsigned*)(coorb + (size_t)N * 32);        // E*16 u32

    (void)hipMemsetAsync(agg, 0, (size_t)N * 32 * sizeof(float), stream);

    coor_kernel<<<nblk, 256, 0, stream>>>(x, coor_w1, coor_w2, coorb, N);

    const long tiles   = ((long)E + 15) / 16;
    const int  lblocks = (int)((tiles + 3) / 4);
    lstm_kernel<0><<<lblocks, 256, 0, stream>>>(edge_traj,
        w_ih_f, w_hh_f, b_ih_f, b_hh_f, cbuf, E);
    lstm_kernel<1><<<lblocks, 256, 0, stream>>>(edge_traj,
        w_ih_b, w_hh_b, b_ih_b, b_hh_b, cbuf, E);

    const int mblocks = (int)((tiles + 4*MTPW - 1) / (4*MTPW));
    msg_kernel<<<mblocks, 256, 0, stream>>>(cbuf, nn2_w1, nn2_w2,
        edge_index, coorb, agg, E);

    agg_kernel<<<nblk, 256, 0, stream>>>(agg, nn_w1, partials, N);
    reduce_kernel<<<1, 256, 0, stream>>>(partials, nn_w2, (float*)d_out, nblk);
}

// Round 9
// 720.625 us; speedup vs baseline: 1.4142x; 1.2405x over previous
//
#include <hip/hip_runtime.h>
#include <hip/hip_bf16.h>

typedef __attribute__((ext_vector_type(8))) short  bf16x8;
typedef __attribute__((ext_vector_type(4))) float  f32x4;

#define MTPW 4   // tiles per wave in msg_kernel
#define LOG2E  1.442695041f
#define LOG2E2 2.885390082f

__device__ __forceinline__ float rcp_(float v){ return __builtin_amdgcn_rcpf(v); }
__device__ __forceinline__ float exp2_(float v){ return __builtin_amdgcn_exp2f(v); }
__device__ __forceinline__ unsigned pk2(float lo, float hi){
    __hip_bfloat162 h = __float22bfloat162_rn(float2{lo, hi});
    return *(unsigned*)&h;
}
__device__ __forceinline__ float lo2f(unsigned u){ return __uint_as_float(u << 16); }
__device__ __forceinline__ float hi2f(unsigned u){ return __uint_as_float(u & 0xFFFF0000u); }

union U4 { bf16x8 v; unsigned u[4]; };

// identity-order 8-column loader
__device__ __forceinline__ bf16x8 ldw8(const float* __restrict__ p){
    const float4 a = *(const float4*)p;
    const float4 b = *(const float4*)(p + 4);
    U4 r;
    r.u[0] = pk2(a.x, a.y); r.u[1] = pk2(a.z, a.w);
    r.u[2] = pk2(b.x, b.y); r.u[3] = pk2(b.z, b.w);
    return r.v;
}
// sigma-permuted loader: slot 8q+j <- column {4q+j (j<4) | 16+4q+j-4}
__device__ __forceinline__ bf16x8 ldw8p(const float* __restrict__ rowp, int lq, float s){
    const float4 a = *(const float4*)(rowp + 4*lq);
    const float4 b = *(const float4*)(rowp + 16 + 4*lq);
    U4 r;
    r.u[0] = pk2(a.x*s, a.y*s); r.u[1] = pk2(a.z*s, a.w*s);
    r.u[2] = pk2(b.x*s, b.y*s); r.u[3] = pk2(b.z*s, b.w*s);
    return r.v;
}
// [Wih | bias | 0] A-fragment (x-MFMA, identity k): lanes lq>0 zero
__device__ __forceinline__ bf16x8 ldihs(const float* __restrict__ wih,
                                        const float* __restrict__ bi,
                                        const float* __restrict__ bh,
                                        int row, int lq, float s){
    U4 r;
    r.u[0] = r.u[1] = r.u[2] = r.u[3] = 0u;
    if (lq == 0) {
        const float* p = wih + row * 6;
        r.u[0] = pk2(p[0]*s, p[1]*s);
        r.u[1] = pk2(p[2]*s, p[3]*s);
        r.u[2] = pk2(p[4]*s, p[5]*s);
        r.u[3] = pk2((bi[row] + bh[row])*s, 0.0f);
    }
    return r.v;
}

// ---------------- kernel 1: coor = relu(x@W1^T)@W2^T -> bf16 [N,32] ----------------
__global__ __launch_bounds__(256) void coor_kernel(
    const float* __restrict__ x, const float* __restrict__ w1,
    const float* __restrict__ w2, unsigned short* __restrict__ coorb, int N)
{
    __shared__ float sW1[96];
    __shared__ float sW2[1024];
    const int tid = threadIdx.x;
    if (tid < 96) sW1[tid] = w1[tid];
    for (int i = tid; i < 1024; i += 256) sW2[i] = w2[i];
    __syncthreads();
    int n = blockIdx.x * 256 + tid;
    if (n >= N) return;
    const float x0 = x[n*3+0], x1 = x[n*3+1], x2 = x[n*3+2];
    float h[32];
#pragma unroll
    for (int k = 0; k < 32; ++k)
        h[k] = fmaxf(sW1[k*3+0]*x0 + sW1[k*3+1]*x1 + sW1[k*3+2]*x2, 0.0f);
    union { uint4 q[4]; unsigned u[16]; } st;
#pragma unroll
    for (int p = 0; p < 16; ++p) {
        float a0 = 0.f, a1 = 0.f;
#pragma unroll
        for (int k = 0; k < 32; ++k) {
            a0 += sW2[(2*p)  *32 + k] * h[k];
            a1 += sW2[(2*p+1)*32 + k] * h[k];
        }
        st.u[p] = pk2(a0, a1);
    }
    uint4* cp = (uint4*)(coorb + (size_t)n * 32);
#pragma unroll
    for (int w = 0; w < 4; ++w) cp[w] = st.q[w];
}

// ---------------- kernel 2: one-direction LSTM, sigma-permuted, shuffle-free ----------------
template<int DIR>
__global__ __launch_bounds__(256, 3) void lstm_kernel(
    const float* __restrict__ edge_traj,
    const float* __restrict__ w_ih, const float* __restrict__ w_hh,
    const float* __restrict__ b_ih, const float* __restrict__ b_hh,
    unsigned* __restrict__ cbuf, int E)
{
    const int lane = threadIdx.x & 63;
    const int wid  = threadIdx.x >> 6;
    const int le   = lane & 15;
    const int lq   = lane >> 4;
    const bool l0  = (lq == 0);
    const f32x4 Z4 = {0.f, 0.f, 0.f, 0.f};

    bf16x8 wh[8], wx[8];
#pragma unroll
    for (int m = 0; m < 8; ++m) {
        const int row = 16*m + le;
        const float s = (m == 4 || m == 5) ? LOG2E2 : -LOG2E;
        wh[m] = ldw8p(w_hh + row*32, lq, s);
        wx[m] = ldihs(w_ih, b_ih, b_hh, row, lq, s);
    }

    const long tile = (long)blockIdx.x * 4 + wid;
    const long e0 = tile * 16;
    if (e0 >= E) return;
    const long er = e0 + le;
    const bool valid = er < E;
    const long ec = valid ? er : (E - 1);
    const float* xb = edge_traj + ec * 48;

    U4 hf; hf.u[0] = hf.u[1] = hf.u[2] = hf.u[3] = 0u;
    float cl[4] = {0,0,0,0}, ch[4] = {0,0,0,0};
#pragma unroll
    for (int t = 0; t < 8; ++t) {
        const int te = DIR ? (7 - t) : t;
        U4 xf;
        {
            const float* xp = xb + te * 6;
            const float2 a  = *(const float2*)xp;
            const float2 b2 = *(const float2*)(xp + 2);
            const float2 c2 = *(const float2*)(xp + 4);
            xf.u[0] = l0 ? pk2(a.x, a.y)   : 0u;
            xf.u[1] = l0 ? pk2(b2.x, b2.y) : 0u;
            xf.u[2] = l0 ? pk2(c2.x, c2.y) : 0u;
            xf.u[3] = l0 ? 0x3f80u         : 0u;   // bias slot = 1.0
        }
        f32x4 acc[8];
#pragma unroll
        for (int m = 0; m < 8; ++m)
            acc[m] = __builtin_amdgcn_mfma_f32_16x16x32_bf16(wx[m], xf.v, Z4, 0, 0, 0);
        if (t > 0) {
#pragma unroll
            for (int m = 0; m < 8; ++m)
                acc[m] = __builtin_amdgcn_mfma_f32_16x16x32_bf16(wh[m], hf.v, acc[m], 0, 0, 0);
        }
        float h_lo[4], h_hi[4];
#pragma unroll
        for (int r = 0; r < 4; ++r) {
            {
                const float Ea = exp2_(acc[0][r]);
                const float Ef = exp2_(acc[2][r]);
                const float Eg = exp2_(acc[4][r]);
                const float Eo = exp2_(acc[6][r]);
                const float p  = (Ea + 1.f) * (Eg + 1.f);
                const float f1 = Ef + 1.f;
                const float num = fmaf(cl[r], p, (Eg - 1.f) * f1);
                cl[r] = num * rcp_(p * f1);
                const float Ec = exp2_(LOG2E2 * cl[r]);
                h_lo[r] = (Ec - 1.f) * rcp_((Eo + 1.f) * (Ec + 1.f));
            }
            {
                const float Ea = exp2_(acc[1][r]);
                const float Ef = exp2_(acc[3][r]);
                const float Eg = exp2_(acc[5][r]);
                const float Eo = exp2_(acc[7][r]);
                const float p  = (Ea + 1.f) * (Eg + 1.f);
                const float f1 = Ef + 1.f;
                const float num = fmaf(ch[r], p, (Eg - 1.f) * f1);
                ch[r] = num * rcp_(p * f1);
                const float Ec = exp2_(LOG2E2 * ch[r]);
                h_hi[r] = (Ec - 1.f) * rcp_((Eo + 1.f) * (Ec + 1.f));
            }
        }
        if (t < 7) {
            hf.u[0] = pk2(h_lo[0], h_lo[1]);
            hf.u[1] = pk2(h_lo[2], h_lo[3]);
            hf.u[2] = pk2(h_hi[0], h_hi[1]);
            hf.u[3] = pk2(h_hi[2], h_hi[3]);
        }
    }

    if (valid) {
        U4 cw;
        cw.u[0] = pk2(cl[0], cl[1]);
        cw.u[1] = pk2(cl[2], cl[3]);
        cw.u[2] = pk2(ch[0], ch[1]);
        cw.u[3] = pk2(ch[2], ch[3]);
        unsigned* dp = cbuf + er * 16 + lq * 4;
        if (DIR == 0) {
            *(uint4*)dp = *(uint4*)cw.u;
        } else {
            const uint4 f = *(const uint4*)dp;
            uint4 o;
            o.x = pk2(0.5f*(lo2f(f.x)+lo2f(cw.u[0])), 0.5f*(hi2f(f.x)+hi2f(cw.u[0])));
            o.y = pk2(0.5f*(lo2f(f.y)+lo2f(cw.u[1])), 0.5f*(hi2f(f.y)+hi2f(cw.u[1])));
            o.z = pk2(0.5f*(lo2f(f.z)+lo2f(cw.u[2])), 0.5f*(hi2f(f.z)+hi2f(cw.u[2])));
            o.w = pk2(0.5f*(lo2f(f.w)+lo2f(cw.u[3])), 0.5f*(hi2f(f.w)+hi2f(cw.u[3])));
            *(uint4*)dp = o;
        }
    }
}

// ---------------- kernel 3: message MLP, writes msg bf16 IN PLACE over tr rows ----------------
// No atomics: each lane reads its own row words then overwrites them (within-lane RAW).
__global__ __launch_bounds__(256, 4) void msg_kernel(
    unsigned* trmsg,                      // [E][16] words, sigma-layout bf16 (in/out)
    const float* __restrict__ nn2_w1, const float* __restrict__ nn2_w2,
    const int* __restrict__ edge_index,
    const unsigned short* __restrict__ coorb, int E)
{
    const int lane = threadIdx.x & 63;
    const int wid  = threadIdx.x >> 6;
    const int le   = lane & 15;
    const int lq   = lane >> 4;
    const f32x4 Z4 = {0.f, 0.f, 0.f, 0.f};

    bf16x8 w1a[2][3], w2a[2];
#pragma unroll
    for (int mm = 0; mm < 2; ++mm) {
        const int row = 16*mm + le;
        w1a[mm][0] = ldw8(nn2_w1 + row*96 +  8*lq);          // coor_dst (identity)
        w1a[mm][1] = ldw8(nn2_w1 + row*96 + 32 + 8*lq);      // coor_src (identity)
        w1a[mm][2] = ldw8p(nn2_w1 + row*96 + 64, lq, 1.0f);  // traj (sigma)
        w2a[mm]    = ldw8p(nn2_w2 + row*32, lq, 1.0f);       // hidden (sigma)
    }

    const long gw = (long)blockIdx.x * 4 + wid;
    for (int it = 0; it < MTPW; ++it) {
        const long tile = gw * MTPW + it;
        const long e0 = tile * 16;
        if (e0 >= E) break;
        const long e_raw = e0 + le;
        const bool valid = e_raw < E;
        const long ec = valid ? e_raw : (E - 1);

        U4 tf;
        if (valid) *(uint4*)tf.u = *(const uint4*)(trmsg + e_raw * 16 + lq * 4);
        else tf.u[0] = tf.u[1] = tf.u[2] = tf.u[3] = 0u;

        const int src = edge_index[ec];
        const int dst = edge_index[E + ec];
        U4 df, sf;
        {
            const uint4 dv = *(const uint4*)(coorb + (size_t)dst*32 + lq*8);
            const uint4 sv = *(const uint4*)(coorb + (size_t)src*32 + lq*8);
            df.u[0]=dv.x; df.u[1]=dv.y; df.u[2]=dv.z; df.u[3]=dv.w;
            sf.u[0]=sv.x; sf.u[1]=sv.y; sf.u[2]=sv.z; sf.u[3]=sv.w;
        }

        f32x4 h1[2];
#pragma unroll
        for (int mm = 0; mm < 2; ++mm) {
            f32x4 a = __builtin_amdgcn_mfma_f32_16x16x32_bf16(w1a[mm][0], df.v, Z4, 0, 0, 0);
            a = __builtin_amdgcn_mfma_f32_16x16x32_bf16(w1a[mm][1], sf.v, a, 0, 0, 0);
            a = __builtin_amdgcn_mfma_f32_16x16x32_bf16(w1a[mm][2], tf.v, a, 0, 0, 0);
            h1[mm] = a;
        }
        U4 gf;
        gf.u[0] = pk2(fmaxf(h1[0][0],0.f), fmaxf(h1[0][1],0.f));
        gf.u[1] = pk2(fmaxf(h1[0][2],0.f), fmaxf(h1[0][3],0.f));
        gf.u[2] = pk2(fmaxf(h1[1][0],0.f), fmaxf(h1[1][1],0.f));
        gf.u[3] = pk2(fmaxf(h1[1][2],0.f), fmaxf(h1[1][3],0.f));

        const f32x4 o0 = __builtin_amdgcn_mfma_f32_16x16x32_bf16(w2a[0], gf.v, Z4, 0, 0, 0);
        const f32x4 o1 = __builtin_amdgcn_mfma_f32_16x16x32_bf16(w2a[1], gf.v, Z4, 0, 0, 0);
        if (valid) {
            U4 cw;
            cw.u[0] = pk2(o0[0], o0[1]);
            cw.u[1] = pk2(o0[2], o0[3]);
            cw.u[2] = pk2(o1[0], o1[1]);
            cw.u[3] = pk2(o1[2], o1[3]);
            *(uint4*)(trmsg + e_raw * 16 + lq * 4) = *(uint4*)cw.u;
        }
    }
}

// ---------------- CSR build ----------------
__global__ __launch_bounds__(256) void hist_kernel(
    const int* __restrict__ ei, int* __restrict__ cnt, int E)
{
    const int e = blockIdx.x*256 + threadIdx.x;
    if (e < E) atomicAdd(&cnt[ei[E + e]], 1);
}

__global__ __launch_bounds__(256) void scan1_kernel(
    const int* __restrict__ cnt, int* __restrict__ bsum, int N)
{
    __shared__ int sp[4];
    const int tid = threadIdx.x;
    const int n = blockIdx.x*256 + tid;
    int c = (n < N) ? cnt[n] : 0;
#pragma unroll
    for (int m = 1; m < 64; m <<= 1) c += __shfl_xor(c, m, 64);
    if ((tid & 63) == 0) sp[tid >> 6] = c;
    __syncthreads();
    if (tid == 0) bsum[blockIdx.x] = sp[0] + sp[1] + sp[2] + sp[3];
}

__global__ __launch_bounds__(512) void scan2_kernel(
    int* __restrict__ bsum, int* __restrict__ offs, int nblk, int E, int N)
{
    __shared__ int s[512];
    const int tid = threadIdx.x;
    const int v = (tid < nblk) ? bsum[tid] : 0;
    s[tid] = v;
    __syncthreads();
    for (int off = 1; off < 512; off <<= 1) {
        const int t = (tid >= off) ? s[tid - off] : 0;
        __syncthreads();
        s[tid] += t;
        __syncthreads();
    }
    if (tid < nblk) bsum[tid] = s[tid] - v;   // exclusive
    if (tid == 0) offs[N] = E;
}

__global__ __launch_bounds__(256) void scan3_kernel(
    const int* __restrict__ cnt, const int* __restrict__ bsum,
    int* __restrict__ offs, int* __restrict__ cursor, int N)
{
    __shared__ int s[256];
    const int tid = threadIdx.x;
    const int n = blockIdx.x*256 + tid;
    const int v = (n < N) ? cnt[n] : 0;
    s[tid] = v;
    __syncthreads();
    for (int off = 1; off < 256; off <<= 1) {
        const int t = (tid >= off) ? s[tid - off] : 0;
        __syncthreads();
        s[tid] += t;
        __syncthreads();
    }
    if (n < N) {
        const int o = bsum[blockIdx.x] + s[tid] - v;
        offs[n] = o;
        cursor[n] = o;
    }
}

__global__ __launch_bounds__(256) void fill_kernel(
    const int* __restrict__ ei, int* __restrict__ cursor,
    int* __restrict__ eidx, int E)
{
    const int e = blockIdx.x*256 + threadIdx.x;
    if (e < E) {
        const int p = atomicAdd(&cursor[ei[E + e]], 1);
        eidx[p] = e;
    }
}

// ---------------- gather: aggv[n][slot] = sum of msg rows of incoming edges ----------------
// wave = 4 nodes x 16 lanes; lane le reads word le of each 64B msg row (coalesced).
__global__ __launch_bounds__(256) void gather_kernel(
    const unsigned* __restrict__ msg, const int* __restrict__ offs,
    const int* __restrict__ eidx, float* __restrict__ aggv, int N)
{
    const int lane = threadIdx.x & 63;
    const int wid  = threadIdx.x >> 6;
    const int g  = lane >> 4;
    const int le = lane & 15;
    const int n = blockIdx.x*16 + wid*4 + g;
    if (n >= N) return;
    const int beg = offs[n], end = offs[n+1];
    float sx = 0.f, sy = 0.f;
    for (int i = beg; i < end; ++i) {
        const unsigned w = msg[(size_t)eidx[i]*16 + le];
        sx += lo2f(w); sy += hi2f(w);
    }
    *(float2*)(aggv + (size_t)n*32 + 2*le) = float2{sx, sy};
}

// ---------------- kernel: partials[b][k] = sum_{n in block} relu(aggv[n]@nn_w1^T)[k] ----------------
// aggv is sigma-slot order -> sW filled with sigma-permuted nn_w1 columns.
__global__ __launch_bounds__(256) void agg_kernel(
    const float* __restrict__ aggv, const float* __restrict__ nn_w1,
    float* __restrict__ partials, int N)
{
    __shared__ float sW[1024];
    __shared__ float sP[4][32];
    const int tid = threadIdx.x;
    for (int i = tid; i < 1024; i += 256) {
        const int jj = i >> 5, s = i & 31, q = s >> 3, j = s & 7;
        const int col = (j < 4) ? (4*q + j) : (16 + 4*q + (j - 4));
        sW[i] = nn_w1[jj*32 + col];
    }
    __syncthreads();
    const int n = blockIdx.x*256 + tid;
    float h[32];
    if (n < N) {
        float a[32];
        const float4* ap = (const float4*)(aggv + (size_t)n*32);
#pragma unroll
        for (int k4 = 0; k4 < 8; ++k4) {
            const float4 v = ap[k4];
            a[k4*4]=v.x; a[k4*4+1]=v.y; a[k4*4+2]=v.z; a[k4*4+3]=v.w;
        }
#pragma unroll
        for (int jj = 0; jj < 32; ++jj) {
            float acc = 0.f;
#pragma unroll
            for (int k = 0; k < 32; ++k) acc += sW[jj*32+k]*a[k];
            h[jj] = fmaxf(acc, 0.f);
        }
    } else {
#pragma unroll
        for (int jj = 0; jj < 32; ++jj) h[jj] = 0.f;
    }
#pragma unroll
    for (int m = 1; m < 64; m <<= 1) {
#pragma unroll
        for (int k = 0; k < 32; ++k) h[k] += __shfl_xor(h[k], m, 64);
    }
    if ((tid & 63) == 0) {
#pragma unroll
        for (int k = 0; k < 32; ++k) sP[tid >> 6][k] = h[k];
    }
    __syncthreads();
    if (tid < 32)
        partials[(size_t)blockIdx.x * 32 + tid]
            = sP[0][tid] + sP[1][tid] + sP[2][tid] + sP[3][tid];
}

// ---------------- final: s32 = sum(partials); out = nn_w2 @ s32 ----------------
__global__ __launch_bounds__(256) void reduce_kernel(
    const float* __restrict__ partials, const float* __restrict__ nn_w2,
    float* __restrict__ out, int nblk)
{
    __shared__ float sR[8][32];
    __shared__ float sS[32];
    const int tid = threadIdx.x;
    const int col = tid & 31;
    const int row = tid >> 5;
    float s = 0.f;
    for (int i = row; i < nblk; i += 8) s += partials[(size_t)i*32 + col];
    sR[row][col] = s;
    __syncthreads();
    if (row == 0) {
        float t = 0.f;
#pragma unroll
        for (int r = 0; r < 8; ++r) t += sR[r][col];
        sS[col] = t;
    }
    __syncthreads();
    if (tid < 64) {
        float acc = 0.f;
#pragma unroll
        for (int k = 0; k < 32; ++k) acc += nn_w2[tid*32+k] * sS[k];
        out[tid] = acc;
    }
}

extern "C" void kernel_launch(void* const* d_in, const int* in_sizes, int n_in,
                              void* d_out, int out_size, void* d_ws, size_t ws_size,
                              hipStream_t stream)
{
    const float* x         = (const float*)d_in[0];
    const float* edge_traj = (const float*)d_in[1];
    const float* w_ih_f    = (const float*)d_in[2];
    const float* w_hh_f    = (const float*)d_in[3];
    const float* b_ih_f    = (const float*)d_in[4];
    const float* b_hh_f    = (const float*)d_in[5];
    const float* w_ih_b    = (const float*)d_in[6];
    const float* w_hh_b    = (const float*)d_in[7];
    const float* b_ih_b    = (const float*)d_in[8];
    const float* b_hh_b    = (const float*)d_in[9];
    const float* coor_w1   = (const float*)d_in[10];
    const float* coor_w2   = (const float*)d_in[11];
    const float* nn2_w1    = (const float*)d_in[12];
    const float* nn2_w2    = (const float*)d_in[13];
    const float* nn_w1     = (const float*)d_in[14];
    const float* nn_w2     = (const float*)d_in[15];
    const int* edge_index  = (const int*)d_in[16];
    const int N = in_sizes[0] / 3;
    const int E = in_sizes[16] / 2;
    const int nblk = (N + 255) / 256;      // 391 (must be <= 512 for scan2)

    float* aggv = (float*)d_ws;                                   // N*32 f32
    float* partials = aggv + (size_t)N * 32;                      // nblk*32 f32
    unsigned short* coorb = (unsigned short*)(partials + (size_t)nblk * 32); // N*32 bf16
    unsigned* cbuf = (unsigned*)(coorb + (size_t)N * 32);         // E*16 u32 (tr -> msg in place)
    int* cnt    = (int*)(cbuf + (size_t)E * 16);                  // N
    int* offs   = cnt + N;                                        // N+1
    int* cursor = offs + N + 1;                                   // N
    int* eidx   = cursor + N;                                     // E
    int* bsum   = eidx + E;                                       // nblk

    (void)hipMemsetAsync(cnt, 0, (size_t)N * sizeof(int), stream);

    coor_kernel<<<nblk, 256, 0, stream>>>(x, coor_w1, coor_w2, coorb, N);

    const long tiles   = ((long)E + 15) / 16;
    const int  lblocks = (int)((tiles + 3) / 4);
    lstm_kernel<0><<<lblocks, 256, 0, stream>>>(edge_traj,
        w_ih_f, w_hh_f, b_ih_f, b_hh_f, cbuf, E);
    lstm_kernel<1><<<lblocks, 256, 0, stream>>>(edge_traj,
        w_ih_b, w_hh_b, b_ih_b, b_hh_b, cbuf, E);

    // CSR build (overlaps conceptually; stream-ordered)
    const int eblk = (E + 255) / 256;
    hist_kernel<<<eblk, 256, 0, stream>>>(edge_index, cnt, E);
    scan1_kernel<<<nblk, 256, 0, stream>>>(cnt, bsum, N);
    scan2_kernel<<<1, 512, 0, stream>>>(bsum, offs, nblk, E, N);
    scan3_kernel<<<nblk, 256, 0, stream>>>(cnt, bsum, offs, cursor, N);
    fill_kernel<<<eblk, 256, 0, stream>>>(edge_index, cursor, eidx, E);

    const int mblocks = (int)((tiles + 4*MTPW - 1) / (4*MTPW));
    msg_kernel<<<mblocks, 256, 0, stream>>>(cbuf, nn2_w1, nn2_w2,
        edge_index, coorb, E);

    gather_kernel<<<(N + 15)/16, 256, 0, stream>>>(cbuf, offs, eidx, aggv, N);
    agg_kernel<<<nblk, 256, 0, stream>>>(aggv, nn_w1, partials, N);
    reduce_kernel<<<1, 256, 0, stream>>>(partials, nn_w2, (float*)d_out, nblk);
}

// Round 10
// 653.269 us; speedup vs baseline: 1.5600x; 1.1031x over previous
//
#include <hip/hip_runtime.h>
#include <hip/hip_bf16.h>

typedef __attribute__((ext_vector_type(8))) short    bf16x8;
typedef __attribute__((ext_vector_type(4))) float    f32x4;
typedef __attribute__((ext_vector_type(4))) unsigned u32x4;

#define MTPW 4   // tiles per wave in msg_kernel
#define LOG2E  1.442695041f
#define LOG2E2 2.885390082f
#define MFMA __builtin_amdgcn_mfma_f32_16x16x32_bf16

__device__ __forceinline__ float rcp_(float v){ return __builtin_amdgcn_rcpf(v); }
__device__ __forceinline__ float exp2_(float v){ return __builtin_amdgcn_exp2f(v); }
__device__ __forceinline__ unsigned pk2(float lo, float hi){
    __hip_bfloat162 h = __float22bfloat162_rn(float2{lo, hi});
    return *(unsigned*)&h;
}
__device__ __forceinline__ float lo2f(unsigned u){ return __uint_as_float(u << 16); }
__device__ __forceinline__ float hi2f(unsigned u){ return __uint_as_float(u & 0xFFFF0000u); }

union U4 { bf16x8 v; unsigned u[4]; };

// identity-order 8-column loader
__device__ __forceinline__ bf16x8 ldw8(const float* __restrict__ p){
    const float4 a = *(const float4*)p;
    const float4 b = *(const float4*)(p + 4);
    U4 r;
    r.u[0] = pk2(a.x, a.y); r.u[1] = pk2(a.z, a.w);
    r.u[2] = pk2(b.x, b.y); r.u[3] = pk2(b.z, b.w);
    return r.v;
}
// sigma-permuted loader: slot 8q+j <- column {4q+j (j<4) | 16+4q+j-4}
__device__ __forceinline__ bf16x8 ldw8p(const float* __restrict__ rowp, int lq, float s){
    const float4 a = *(const float4*)(rowp + 4*lq);
    const float4 b = *(const float4*)(rowp + 16 + 4*lq);
    U4 r;
    r.u[0] = pk2(a.x*s, a.y*s); r.u[1] = pk2(a.z*s, a.w*s);
    r.u[2] = pk2(b.x*s, b.y*s); r.u[3] = pk2(b.z*s, b.w*s);
    return r.v;
}

// 8 x ds_read_b128 + single waitcnt, volatile so reads are re-issued per step
// (register file is too small to keep weights resident at good occupancy).
#define LDS_RD8(d0,d1,d2,d3,d4,d5,d6,d7,O0,O1,O2,O3,O4,O5,O6,O7)            \
  asm volatile("ds_read_b128 %0, %8 offset:" O0 "\n\t"                      \
               "ds_read_b128 %1, %8 offset:" O1 "\n\t"                      \
               "ds_read_b128 %2, %8 offset:" O2 "\n\t"                      \
               "ds_read_b128 %3, %8 offset:" O3 "\n\t"                      \
               "ds_read_b128 %4, %8 offset:" O4 "\n\t"                      \
               "ds_read_b128 %5, %8 offset:" O5 "\n\t"                      \
               "ds_read_b128 %6, %8 offset:" O6 "\n\t"                      \
               "ds_read_b128 %7, %8 offset:" O7 "\n\t"                      \
               "s_waitcnt lgkmcnt(0)"                                       \
               : "=&v"(d0),"=&v"(d1),"=&v"(d2),"=&v"(d3),                   \
                 "=&v"(d4),"=&v"(d5),"=&v"(d6),"=&v"(d7)                    \
               : "v"(lds_addr))

__device__ __forceinline__ bf16x8 bc8(u32x4 x){ return __builtin_bit_cast(bf16x8, x); }

// merged-rcp LSTM gate update for 4 units: Ea=e^-i, Ef=e^-f, Eg=e^2g, Eo=e^-o
__device__ __forceinline__ void gates4(const f32x4 ai, const f32x4 af,
                                       const f32x4 ag, const f32x4 ao,
                                       float c[4], float h[4]){
#pragma unroll
    for (int r = 0; r < 4; ++r) {
        const float Ea = exp2_(ai[r]);
        const float Ef = exp2_(af[r]);
        const float Eg = exp2_(ag[r]);
        const float Eo = exp2_(ao[r]);
        const float p  = (Ea + 1.f) * (Eg + 1.f);
        const float f1 = Ef + 1.f;
        const float num = fmaf(c[r], p, (Eg - 1.f) * f1);
        c[r] = num * rcp_(p * f1);
        const float Ec = exp2_(LOG2E2 * c[r]);
        h[r] = (Ec - 1.f) * rcp_((Eo + 1.f) * (Ec + 1.f));
    }
}

// ---------------- kernel 1: coor = relu(x@W1^T)@W2^T -> bf16 [N,32] ----------------
__global__ __launch_bounds__(256) void coor_kernel(
    const float* __restrict__ x, const float* __restrict__ w1,
    const float* __restrict__ w2, unsigned short* __restrict__ coorb, int N)
{
    __shared__ float sW1[96];
    __shared__ float sW2[1024];
    const int tid = threadIdx.x;
    if (tid < 96) sW1[tid] = w1[tid];
    for (int i = tid; i < 1024; i += 256) sW2[i] = w2[i];
    __syncthreads();
    int n = blockIdx.x * 256 + tid;
    if (n >= N) return;
    const float x0 = x[n*3+0], x1 = x[n*3+1], x2 = x[n*3+2];
    float h[32];
#pragma unroll
    for (int k = 0; k < 32; ++k)
        h[k] = fmaxf(sW1[k*3+0]*x0 + sW1[k*3+1]*x1 + sW1[k*3+2]*x2, 0.0f);
    union { uint4 q[4]; unsigned u[16]; } st;
#pragma unroll
    for (int p = 0; p < 16; ++p) {
        float a0 = 0.f, a1 = 0.f;
#pragma unroll
        for (int k = 0; k < 32; ++k) {
            a0 += sW2[(2*p)  *32 + k] * h[k];
            a1 += sW2[(2*p+1)*32 + k] * h[k];
        }
        st.u[p] = pk2(a0, a1);
    }
    uint4* cp = (uint4*)(coorb + (size_t)n * 32);
#pragma unroll
    for (int w = 0; w < 4; ++w) cp[w] = st.q[w];
}

// ---------------- kernel 2: one-direction LSTM, 2 tiles/wave, weights in LDS ----------------
// LDS layout (16KB): wh fragment entries [m*64+lane] (16B each) at byte m*1024+lane*16;
// wx entries at 8192 + m*1024 + lane*16. All fragments sigma-permuted + scale-folded.
// Per step: read lo m-group {0,2,4,6} (gates i,f,g,o of lo half), MFMA both tiles,
// read hi group (overlaps MFMA latency), gate math, repeat for hi.
template<int DIR>
__global__ __launch_bounds__(256, 2) void lstm_kernel(
    const float* __restrict__ edge_traj,
    const float* __restrict__ w_ih, const float* __restrict__ w_hh,
    const float* __restrict__ b_ih, const float* __restrict__ b_hh,
    unsigned* __restrict__ cbuf, int E)
{
    __shared__ unsigned lds_w[4096];
    const int tid = threadIdx.x;
    for (int i = tid; i < 512; i += 256) {
        const int m = i >> 6, ln = i & 63;
        const int le2 = ln & 15, lq2 = ln >> 4;
        const int row = 16*m + le2;
        const float s = (m == 4 || m == 5) ? LOG2E2 : -LOG2E;
        const float4 a = *(const float4*)(w_hh + row*32 + 4*lq2);
        const float4 b = *(const float4*)(w_hh + row*32 + 16 + 4*lq2);
        unsigned* wp = &lds_w[(size_t)i * 4];
        wp[0] = pk2(a.x*s, a.y*s); wp[1] = pk2(a.z*s, a.w*s);
        wp[2] = pk2(b.x*s, b.y*s); wp[3] = pk2(b.z*s, b.w*s);
        unsigned* xp = &lds_w[(size_t)(512 + i) * 4];
        if (lq2 == 0) {
            const float* p = w_ih + row * 6;
            xp[0] = pk2(p[0]*s, p[1]*s);
            xp[1] = pk2(p[2]*s, p[3]*s);
            xp[2] = pk2(p[4]*s, p[5]*s);
            xp[3] = pk2((b_ih[row] + b_hh[row])*s, 0.f);
        } else {
            xp[0] = 0u; xp[1] = 0u; xp[2] = 0u; xp[3] = 0u;
        }
    }
    __syncthreads();

    const int lane = tid & 63;
    const int wid  = tid >> 6;
    const int le   = lane & 15;
    const int lq   = lane >> 4;
    const bool l0  = (lq == 0);
    const unsigned lds_addr = (unsigned)(size_t)lds_w + (unsigned)lane * 16u;
    const f32x4 Z4 = {0.f, 0.f, 0.f, 0.f};

    const long pr = (long)blockIdx.x * 4 + wid;
    const long e0 = pr * 32;
    if (e0 >= E) return;
    const long eA = e0 + le, eB = e0 + 16 + le;
    const bool vA = eA < E, vB = eB < E;
    const float* xbA = edge_traj + (vA ? eA : (E - 1)) * 48;
    const float* xbB = edge_traj + (vB ? eB : (E - 1)) * 48;

    U4 hfA, hfB;
    hfA.u[0]=hfA.u[1]=hfA.u[2]=hfA.u[3]=0u;
    hfB.u[0]=hfB.u[1]=hfB.u[2]=hfB.u[3]=0u;
    float clA[4]={0,0,0,0}, chA[4]={0,0,0,0};
    float clB[4]={0,0,0,0}, chB[4]={0,0,0,0};

#pragma unroll
    for (int t = 0; t < 8; ++t) {
        const int te = DIR ? (7 - t) : t;
        U4 xfA, xfB;
        {
            const float* xp = xbA + te * 6;
            const float2 a  = *(const float2*)xp;
            const float2 b2 = *(const float2*)(xp + 2);
            const float2 c2 = *(const float2*)(xp + 4);
            xfA.u[0] = l0 ? pk2(a.x, a.y)   : 0u;
            xfA.u[1] = l0 ? pk2(b2.x, b2.y) : 0u;
            xfA.u[2] = l0 ? pk2(c2.x, c2.y) : 0u;
            xfA.u[3] = l0 ? 0x3f80u         : 0u;
        }
        {
            const float* xp = xbB + te * 6;
            const float2 a  = *(const float2*)xp;
            const float2 b2 = *(const float2*)(xp + 2);
            const float2 c2 = *(const float2*)(xp + 4);
            xfB.u[0] = l0 ? pk2(a.x, a.y)   : 0u;
            xfB.u[1] = l0 ? pk2(b2.x, b2.y) : 0u;
            xfB.u[2] = l0 ? pk2(c2.x, c2.y) : 0u;
            xfB.u[3] = l0 ? 0x3f80u         : 0u;
        }

        // ---- lo m-group {0,2,4,6}: wh at 0/2048/4096/6144, wx at +8192
        u32x4 f0,f1,f2,f3,f4,f5,f6,f7;
        LDS_RD8(f0,f1,f2,f3,f4,f5,f6,f7,
                "0","2048","4096","6144","8192","10240","12288","14336");
        f32x4 aiA = MFMA(bc8(f4), xfA.v, Z4, 0,0,0);
        f32x4 afA = MFMA(bc8(f5), xfA.v, Z4, 0,0,0);
        f32x4 agA = MFMA(bc8(f6), xfA.v, Z4, 0,0,0);
        f32x4 aoA = MFMA(bc8(f7), xfA.v, Z4, 0,0,0);
        f32x4 aiB = MFMA(bc8(f4), xfB.v, Z4, 0,0,0);
        f32x4 afB = MFMA(bc8(f5), xfB.v, Z4, 0,0,0);
        f32x4 agB = MFMA(bc8(f6), xfB.v, Z4, 0,0,0);
        f32x4 aoB = MFMA(bc8(f7), xfB.v, Z4, 0,0,0);
        if (t > 0) {
            aiA = MFMA(bc8(f0), hfA.v, aiA, 0,0,0);
            afA = MFMA(bc8(f1), hfA.v, afA, 0,0,0);
            agA = MFMA(bc8(f2), hfA.v, agA, 0,0,0);
            aoA = MFMA(bc8(f3), hfA.v, aoA, 0,0,0);
            aiB = MFMA(bc8(f0), hfB.v, aiB, 0,0,0);
            afB = MFMA(bc8(f1), hfB.v, afB, 0,0,0);
            agB = MFMA(bc8(f2), hfB.v, agB, 0,0,0);
            aoB = MFMA(bc8(f3), hfB.v, aoB, 0,0,0);
        }
        // ---- hi m-group reads overlap the lo MFMA latency
        u32x4 g0,g1,g2,g3,g4,g5,g6,g7;
        LDS_RD8(g0,g1,g2,g3,g4,g5,g6,g7,
                "1024","3072","5120","7168","9216","11264","13312","15360");
        float hlA[4], hlB[4];
        gates4(aiA, afA, agA, aoA, clA, hlA);
        gates4(aiB, afB, agB, aoB, clB, hlB);

        f32x4 biA = MFMA(bc8(g4), xfA.v, Z4, 0,0,0);
        f32x4 bfA = MFMA(bc8(g5), xfA.v, Z4, 0,0,0);
        f32x4 bgA = MFMA(bc8(g6), xfA.v, Z4, 0,0,0);
        f32x4 boA = MFMA(bc8(g7), xfA.v, Z4, 0,0,0);
        f32x4 biB = MFMA(bc8(g4), xfB.v, Z4, 0,0,0);
        f32x4 bfB = MFMA(bc8(g5), xfB.v, Z4, 0,0,0);
        f32x4 bgB = MFMA(bc8(g6), xfB.v, Z4, 0,0,0);
        f32x4 boB = MFMA(bc8(g7), xfB.v, Z4, 0,0,0);
        if (t > 0) {
            biA = MFMA(bc8(g0), hfA.v, biA, 0,0,0);
            bfA = MFMA(bc8(g1), hfA.v, bfA, 0,0,0);
            bgA = MFMA(bc8(g2), hfA.v, bgA, 0,0,0);
            boA = MFMA(bc8(g3), hfA.v, boA, 0,0,0);
            biB = MFMA(bc8(g0), hfB.v, biB, 0,0,0);
            bfB = MFMA(bc8(g1), hfB.v, bfB, 0,0,0);
            bgB = MFMA(bc8(g2), hfB.v, bgB, 0,0,0);
            boB = MFMA(bc8(g3), hfB.v, boB, 0,0,0);
        }
        float hhA[4], hhB[4];
        gates4(biA, bfA, bgA, boA, chA, hhA);
        gates4(biB, bfB, bgB, boB, chB, hhB);

        if (t < 7) {
            hfA.u[0] = pk2(hlA[0], hlA[1]); hfA.u[1] = pk2(hlA[2], hlA[3]);
            hfA.u[2] = pk2(hhA[0], hhA[1]); hfA.u[3] = pk2(hhA[2], hhA[3]);
            hfB.u[0] = pk2(hlB[0], hlB[1]); hfB.u[1] = pk2(hlB[2], hlB[3]);
            hfB.u[2] = pk2(hhB[0], hhB[1]); hfB.u[3] = pk2(hhB[2], hhB[3]);
        }
    }

    // c -> sigma-layout e-major bf16
#pragma unroll
    for (int p = 0; p < 2; ++p) {
        const float* cl = p ? clB : clA;
        const float* ch = p ? chB : chA;
        const bool  vst = p ? vB : vA;
        const long  er  = p ? eB : eA;
        if (!vst) continue;
        U4 cw;
        cw.u[0] = pk2(cl[0], cl[1]);
        cw.u[1] = pk2(cl[2], cl[3]);
        cw.u[2] = pk2(ch[0], ch[1]);
        cw.u[3] = pk2(ch[2], ch[3]);
        unsigned* dp = cbuf + er * 16 + lq * 4;
        if (DIR == 0) {
            *(uint4*)dp = *(uint4*)cw.u;
        } else {
            const uint4 f = *(const uint4*)dp;
            uint4 o;
            o.x = pk2(0.5f*(lo2f(f.x)+lo2f(cw.u[0])), 0.5f*(hi2f(f.x)+hi2f(cw.u[0])));
            o.y = pk2(0.5f*(lo2f(f.y)+lo2f(cw.u[1])), 0.5f*(hi2f(f.y)+hi2f(cw.u[1])));
            o.z = pk2(0.5f*(lo2f(f.z)+lo2f(cw.u[2])), 0.5f*(hi2f(f.z)+hi2f(cw.u[2])));
            o.w = pk2(0.5f*(lo2f(f.w)+lo2f(cw.u[3])), 0.5f*(hi2f(f.w)+hi2f(cw.u[3])));
            *(uint4*)dp = o;
        }
    }
}

// ---------------- kernel 3: message MLP, writes msg bf16 IN PLACE over tr rows ----------------
__global__ __launch_bounds__(256, 4) void msg_kernel(
    unsigned* trmsg,
    const float* __restrict__ nn2_w1, const float* __restrict__ nn2_w2,
    const int* __restrict__ edge_index,
    const unsigned short* __restrict__ coorb, int E)
{
    const int lane = threadIdx.x & 63;
    const int wid  = threadIdx.x >> 6;
    const int le   = lane & 15;
    const int lq   = lane >> 4;
    const f32x4 Z4 = {0.f, 0.f, 0.f, 0.f};

    bf16x8 w1a[2][3], w2a[2];
#pragma unroll
    for (int mm = 0; mm < 2; ++mm) {
        const int row = 16*mm + le;
        w1a[mm][0] = ldw8(nn2_w1 + row*96 +  8*lq);
        w1a[mm][1] = ldw8(nn2_w1 + row*96 + 32 + 8*lq);
        w1a[mm][2] = ldw8p(nn2_w1 + row*96 + 64, lq, 1.0f);
        w2a[mm]    = ldw8p(nn2_w2 + row*32, lq, 1.0f);
    }

    const long gw = (long)blockIdx.x * 4 + wid;
    for (int it = 0; it < MTPW; ++it) {
        const long tile = gw * MTPW + it;
        const long e0 = tile * 16;
        if (e0 >= E) break;
        const long e_raw = e0 + le;
        const bool valid = e_raw < E;
        const long ec = valid ? e_raw : (E - 1);

        U4 tf;
        if (valid) *(uint4*)tf.u = *(const uint4*)(trmsg + e_raw * 16 + lq * 4);
        else tf.u[0] = tf.u[1] = tf.u[2] = tf.u[3] = 0u;

        const int src = edge_index[ec];
        const int dst = edge_index[E + ec];
        U4 df, sf;
        {
            const uint4 dv = *(const uint4*)(coorb + (size_t)dst*32 + lq*8);
            const uint4 sv = *(const uint4*)(coorb + (size_t)src*32 + lq*8);
            df.u[0]=dv.x; df.u[1]=dv.y; df.u[2]=dv.z; df.u[3]=dv.w;
            sf.u[0]=sv.x; sf.u[1]=sv.y; sf.u[2]=sv.z; sf.u[3]=sv.w;
        }

        f32x4 h1[2];
#pragma unroll
        for (int mm = 0; mm < 2; ++mm) {
            f32x4 a = MFMA(w1a[mm][0], df.v, Z4, 0,0,0);
            a = MFMA(w1a[mm][1], sf.v, a, 0,0,0);
            a = MFMA(w1a[mm][2], tf.v, a, 0,0,0);
            h1[mm] = a;
        }
        U4 gf;
        gf.u[0] = pk2(fmaxf(h1[0][0],0.f), fmaxf(h1[0][1],0.f));
        gf.u[1] = pk2(fmaxf(h1[0][2],0.f), fmaxf(h1[0][3],0.f));
        gf.u[2] = pk2(fmaxf(h1[1][0],0.f), fmaxf(h1[1][1],0.f));
        gf.u[3] = pk2(fmaxf(h1[1][2],0.f), fmaxf(h1[1][3],0.f));

        const f32x4 o0 = MFMA(w2a[0], gf.v, Z4, 0,0,0);
        const f32x4 o1 = MFMA(w2a[1], gf.v, Z4, 0,0,0);
        if (valid) {
            U4 cw;
            cw.u[0] = pk2(o0[0], o0[1]);
            cw.u[1] = pk2(o0[2], o0[3]);
            cw.u[2] = pk2(o1[0], o1[1]);
            cw.u[3] = pk2(o1[2], o1[3]);
            *(uint4*)(trmsg + e_raw * 16 + lq * 4) = *(uint4*)cw.u;
        }
    }
}

// ---------------- CSR build ----------------
__global__ __launch_bounds__(256) void hist_kernel(
    const int* __restrict__ ei, int* __restrict__ cnt, int E)
{
    const int e = blockIdx.x*256 + threadIdx.x;
    if (e < E) atomicAdd(&cnt[ei[E + e]], 1);
}

__global__ __launch_bounds__(256) void scan1_kernel(
    const int* __restrict__ cnt, int* __restrict__ bsum, int N)
{
    __shared__ int sp[4];
    const int tid = threadIdx.x;
    const int n = blockIdx.x*256 + tid;
    int c = (n < N) ? cnt[n] : 0;
#pragma unroll
    for (int m = 1; m < 64; m <<= 1) c += __shfl_xor(c, m, 64);
    if ((tid & 63) == 0) sp[tid >> 6] = c;
    __syncthreads();
    if (tid == 0) bsum[blockIdx.x] = sp[0] + sp[1] + sp[2] + sp[3];
}

__global__ __launch_bounds__(512) void scan2_kernel(
    int* __restrict__ bsum, int* __restrict__ offs, int nblk, int E, int N)
{
    __shared__ int s[512];
    const int tid = threadIdx.x;
    const int v = (tid < nblk) ? bsum[tid] : 0;
    s[tid] = v;
    __syncthreads();
    for (int off = 1; off < 512; off <<= 1) {
        const int t = (tid >= off) ? s[tid - off] : 0;
        __syncthreads();
        s[tid] += t;
        __syncthreads();
    }
    if (tid < nblk) bsum[tid] = s[tid] - v;
    if (tid == 0) offs[N] = E;
}

__global__ __launch_bounds__(256) void scan3_kernel(
    const int* __restrict__ cnt, const int* __restrict__ bsum,
    int* __restrict__ offs, int* __restrict__ cursor, int N)
{
    __shared__ int s[256];
    const int tid = threadIdx.x;
    const int n = blockIdx.x*256 + tid;
    const int v = (n < N) ? cnt[n] : 0;
    s[tid] = v;
    __syncthreads();
    for (int off = 1; off < 256; off <<= 1) {
        const int t = (tid >= off) ? s[tid - off] : 0;
        __syncthreads();
        s[tid] += t;
        __syncthreads();
    }
    if (n < N) {
        const int o = bsum[blockIdx.x] + s[tid] - v;
        offs[n] = o;
        cursor[n] = o;
    }
}

__global__ __launch_bounds__(256) void fill_kernel(
    const int* __restrict__ ei, int* __restrict__ cursor,
    int* __restrict__ eidx, int E)
{
    const int e = blockIdx.x*256 + threadIdx.x;
    if (e < E) {
        const int p = atomicAdd(&cursor[ei[E + e]], 1);
        eidx[p] = e;
    }
}

// ---------------- gather: aggv[n][slot] = sum of msg rows of incoming edges ----------------
__global__ __launch_bounds__(256) void gather_kernel(
    const unsigned* __restrict__ msg, const int* __restrict__ offs,
    const int* __restrict__ eidx, float* __restrict__ aggv, int N)
{
    const int lane = threadIdx.x & 63;
    const int wid  = threadIdx.x >> 6;
    const int g  = lane >> 4;
    const int le = lane & 15;
    const int n = blockIdx.x*16 + wid*4 + g;
    if (n >= N) return;
    const int beg = offs[n], end = offs[n+1];
    float sx = 0.f, sy = 0.f;
    for (int i = beg; i < end; ++i) {
        const unsigned w = msg[(size_t)eidx[i]*16 + le];
        sx += lo2f(w); sy += hi2f(w);
    }
    *(float2*)(aggv + (size_t)n*32 + 2*le) = float2{sx, sy};
}

// ---------------- agg: partials[b][k] = sum_{n in block} relu(aggv[n]@nn_w1^T)[k] ----------------
__global__ __launch_bounds__(256) void agg_kernel(
    const float* __restrict__ aggv, const float* __restrict__ nn_w1,
    float* __restrict__ partials, int N)
{
    __shared__ float sW[1024];
    __shared__ float sP[4][32];
    const int tid = threadIdx.x;
    for (int i = tid; i < 1024; i += 256) {
        const int jj = i >> 5, s = i & 31, q = s >> 3, j = s & 7;
        const int col = (j < 4) ? (4*q + j) : (16 + 4*q + (j - 4));
        sW[i] = nn_w1[jj*32 + col];
    }
    __syncthreads();
    const int n = blockIdx.x*256 + tid;
    float h[32];
    if (n < N) {
        float a[32];
        const float4* ap = (const float4*)(aggv + (size_t)n*32);
#pragma unroll
        for (int k4 = 0; k4 < 8; ++k4) {
            const float4 v = ap[k4];
            a[k4*4]=v.x; a[k4*4+1]=v.y; a[k4*4+2]=v.z; a[k4*4+3]=v.w;
        }
#pragma unroll
        for (int jj = 0; jj < 32; ++jj) {
            float acc = 0.f;
#pragma unroll
            for (int k = 0; k < 32; ++k) acc += sW[jj*32+k]*a[k];
            h[jj] = fmaxf(acc, 0.f);
        }
    } else {
#pragma unroll
        for (int jj = 0; jj < 32; ++jj) h[jj] = 0.f;
    }
#pragma unroll
    for (int m = 1; m < 64; m <<= 1) {
#pragma unroll
        for (int k = 0; k < 32; ++k) h[k] += __shfl_xor(h[k], m, 64);
    }
    if ((tid & 63) == 0) {
#pragma unroll
        for (int k = 0; k < 32; ++k) sP[tid >> 6][k] = h[k];
    }
    __syncthreads();
    if (tid < 32)
        partials[(size_t)blockIdx.x * 32 + tid]
            = sP[0][tid] + sP[1][tid] + sP[2][tid] + sP[3][tid];
}

// ---------------- final: s32 = sum(partials); out = nn_w2 @ s32 ----------------
__global__ __launch_bounds__(256) void reduce_kernel(
    const float* __restrict__ partials, const float* __restrict__ nn_w2,
    float* __restrict__ out, int nblk)
{
    __shared__ float sR[8][32];
    __shared__ float sS[32];
    const int tid = threadIdx.x;
    const int col = tid & 31;
    const int row = tid >> 5;
    float s = 0.f;
    for (int i = row; i < nblk; i += 8) s += partials[(size_t)i*32 + col];
    sR[row][col] = s;
    __syncthreads();
    if (row == 0) {
        float t = 0.f;
#pragma unroll
        for (int r = 0; r < 8; ++r) t += sR[r][col];
        sS[col] = t;
    }
    __syncthreads();
    if (tid < 64) {
        float acc = 0.f;
#pragma unroll
        for (int k = 0; k < 32; ++k) acc += nn_w2[tid*32+k] * sS[k];
        out[tid] = acc;
    }
}

extern "C" void kernel_launch(void* const* d_in, const int* in_sizes, int n_in,
                              void* d_out, int out_size, void* d_ws, size_t ws_size,
                              hipStream_t stream)
{
    const float* x         = (const float*)d_in[0];
    const float* edge_traj = (const float*)d_in[1];
    const float* w_ih_f    = (const float*)d_in[2];
    const float* w_hh_f    = (const float*)d_in[3];
    const float* b_ih_f    = (const float*)d_in[4];
    const float* b_hh_f    = (const float*)d_in[5];
    const float* w_ih_b    = (const float*)d_in[6];
    const float* w_hh_b    = (const float*)d_in[7];
    const float* b_ih_b    = (const float*)d_in[8];
    const float* b_hh_b    = (const float*)d_in[9];
    const float* coor_w1   = (const float*)d_in[10];
    const float* coor_w2   = (const float*)d_in[11];
    const float* nn2_w1    = (const float*)d_in[12];
    const float* nn2_w2    = (const float*)d_in[13];
    const float* nn_w1     = (const float*)d_in[14];
    const float* nn_w2     = (const float*)d_in[15];
    const int* edge_index  = (const int*)d_in[16];
    const int N = in_sizes[0] / 3;
    const int E = in_sizes[16] / 2;
    const int nblk = (N + 255) / 256;

    float* aggv = (float*)d_ws;                                   // N*32 f32
    float* partials = aggv + (size_t)N * 32;                      // nblk*32 f32
    unsigned short* coorb = (unsigned short*)(partials + (size_t)nblk * 32); // N*32 bf16
    unsigned* cbuf = (unsigned*)(coorb + (size_t)N * 32);         // E*16 u32
    int* cnt    = (int*)(cbuf + (size_t)E * 16);                  // N
    int* offs   = cnt + N;                                        // N+1
    int* cursor = offs + N + 1;                                   // N
    int* eidx   = cursor + N;                                     // E
    int* bsum   = eidx + E;                                       // nblk

    (void)hipMemsetAsync(cnt, 0, (size_t)N * sizeof(int), stream);

    coor_kernel<<<nblk, 256, 0, stream>>>(x, coor_w1, coor_w2, coorb, N);

    const long tiles   = ((long)E + 15) / 16;
    const long pairs   = (tiles + 1) / 2;
    const int  lblocks = (int)((pairs + 3) / 4);
    lstm_kernel<0><<<lblocks, 256, 0, stream>>>(edge_traj,
        w_ih_f, w_hh_f, b_ih_f, b_hh_f, cbuf, E);
    lstm_kernel<1><<<lblocks, 256, 0, stream>>>(edge_traj,
        w_ih_b, w_hh_b, b_ih_b, b_hh_b, cbuf, E);

    const int eblk = (E + 255) / 256;
    hist_kernel<<<eblk, 256, 0, stream>>>(edge_index, cnt, E);
    scan1_kernel<<<nblk, 256, 0, stream>>>(cnt, bsum, N);
    scan2_kernel<<<1, 512, 0, stream>>>(bsum, offs, nblk, E, N);
    scan3_kernel<<<nblk, 256, 0, stream>>>(cnt, bsum, offs, cursor, N);
    fill_kernel<<<eblk, 256, 0, stream>>>(edge_index, cursor, eidx, E);

    const int mblocks = (int)((tiles + 4*MTPW - 1) / (4*MTPW));
    msg_kernel<<<mblocks, 256, 0, stream>>>(cbuf, nn2_w1, nn2_w2,
        edge_index, coorb, E);

    gather_kernel<<<(N + 15)/16, 256, 0, stream>>>(cbuf, offs, eidx, aggv, N);
    agg_kernel<<<nblk, 256, 0, stream>>>(aggv, nn_w1, partials, N);
    reduce_kernel<<<1, 256, 0, stream>>>(partials, nn_w2, (float*)d_out, nblk);
}

// Round 11
// 607.027 us; speedup vs baseline: 1.6788x; 1.0762x over previous
//
#include <hip/hip_runtime.h>
#include <hip/hip_bf16.h>

typedef __attribute__((ext_vector_type(8))) short    bf16x8;
typedef __attribute__((ext_vector_type(4))) float    f32x4;
typedef __attribute__((ext_vector_type(4))) unsigned u32x4;

#define MTPW 4   // tiles per wave in msg_kernel
#define LOG2E  1.442695041f
#define LOG2E2 2.885390082f
#define MFMA __builtin_amdgcn_mfma_f32_16x16x32_bf16

__device__ __forceinline__ float rcp_(float v){ return __builtin_amdgcn_rcpf(v); }
__device__ __forceinline__ float exp2_(float v){ return __builtin_amdgcn_exp2f(v); }
__device__ __forceinline__ unsigned pk2(float lo, float hi){
    __hip_bfloat162 h = __float22bfloat162_rn(float2{lo, hi});
    return *(unsigned*)&h;
}
__device__ __forceinline__ float lo2f(unsigned u){ return __uint_as_float(u << 16); }
__device__ __forceinline__ float hi2f(unsigned u){ return __uint_as_float(u & 0xFFFF0000u); }

union U4 { bf16x8 v; unsigned u[4]; };

// identity-order 8-column loader
__device__ __forceinline__ bf16x8 ldw8(const float* __restrict__ p){
    const float4 a = *(const float4*)p;
    const float4 b = *(const float4*)(p + 4);
    U4 r;
    r.u[0] = pk2(a.x, a.y); r.u[1] = pk2(a.z, a.w);
    r.u[2] = pk2(b.x, b.y); r.u[3] = pk2(b.z, b.w);
    return r.v;
}
// sigma-permuted loader: slot 8q+j <- column {4q+j (j<4) | 16+4q+j-4}
__device__ __forceinline__ bf16x8 ldw8p(const float* __restrict__ rowp, int lq, float s){
    const float4 a = *(const float4*)(rowp + 4*lq);
    const float4 b = *(const float4*)(rowp + 16 + 4*lq);
    U4 r;
    r.u[0] = pk2(a.x*s, a.y*s); r.u[1] = pk2(a.z*s, a.w*s);
    r.u[2] = pk2(b.x*s, b.y*s); r.u[3] = pk2(b.z*s, b.w*s);
    return r.v;
}

// 8 x ds_read_b128 + single waitcnt, volatile so reads re-issue per step
#define LDS_RD8(d0,d1,d2,d3,d4,d5,d6,d7,O0,O1,O2,O3,O4,O5,O6,O7)            \
  asm volatile("ds_read_b128 %0, %8 offset:" O0 "\n\t"                      \
               "ds_read_b128 %1, %8 offset:" O1 "\n\t"                      \
               "ds_read_b128 %2, %8 offset:" O2 "\n\t"                      \
               "ds_read_b128 %3, %8 offset:" O3 "\n\t"                      \
               "ds_read_b128 %4, %8 offset:" O4 "\n\t"                      \
               "ds_read_b128 %5, %8 offset:" O5 "\n\t"                      \
               "ds_read_b128 %6, %8 offset:" O6 "\n\t"                      \
               "ds_read_b128 %7, %8 offset:" O7 "\n\t"                      \
               "s_waitcnt lgkmcnt(0)"                                       \
               : "=&v"(d0),"=&v"(d1),"=&v"(d2),"=&v"(d3),                   \
                 "=&v"(d4),"=&v"(d5),"=&v"(d6),"=&v"(d7)                    \
               : "v"(lds_addr))

__device__ __forceinline__ bf16x8 bc8(u32x4 x){ return __builtin_bit_cast(bf16x8, x); }

// merged-rcp LSTM gate updates. Ea=e^-i, Ef=e^-f, Eg=e^2g, Eo=e^-o (scales folded
// into weights). Variants: first (t=0, c_in=0, no f-gate), mid, last (t=7, no h).
__device__ __forceinline__ void gates4_first(const f32x4 ai, const f32x4 ag, const f32x4 ao,
                                             float c[4], float h[4]){
#pragma unroll
    for (int r = 0; r < 4; ++r) {
        const float Ea = exp2_(ai[r]);
        const float Eg = exp2_(ag[r]);
        const float Eo = exp2_(ao[r]);
        c[r] = (Eg - 1.f) * rcp_((Ea + 1.f) * (Eg + 1.f));
        const float Ec = exp2_(LOG2E2 * c[r]);
        h[r] = (Ec - 1.f) * rcp_((Eo + 1.f) * (Ec + 1.f));
    }
}
__device__ __forceinline__ void gates4_mid(const f32x4 ai, const f32x4 af,
                                           const f32x4 ag, const f32x4 ao,
                                           float c[4], float h[4]){
#pragma unroll
    for (int r = 0; r < 4; ++r) {
        const float Ea = exp2_(ai[r]);
        const float Ef = exp2_(af[r]);
        const float Eg = exp2_(ag[r]);
        const float Eo = exp2_(ao[r]);
        const float p  = (Ea + 1.f) * (Eg + 1.f);
        const float f1 = Ef + 1.f;
        const float num = fmaf(c[r], p, (Eg - 1.f) * f1);
        c[r] = num * rcp_(p * f1);
        const float Ec = exp2_(LOG2E2 * c[r]);
        h[r] = (Ec - 1.f) * rcp_((Eo + 1.f) * (Ec + 1.f));
    }
}
__device__ __forceinline__ void gates4_last(const f32x4 ai, const f32x4 af,
                                            const f32x4 ag, float c[4]){
#pragma unroll
    for (int r = 0; r < 4; ++r) {
        const float Ea = exp2_(ai[r]);
        const float Ef = exp2_(af[r]);
        const float Eg = exp2_(ag[r]);
        const float p  = (Ea + 1.f) * (Eg + 1.f);
        const float f1 = Ef + 1.f;
        const float num = fmaf(c[r], p, (Eg - 1.f) * f1);
        c[r] = num * rcp_(p * f1);
    }
}

// ---------------- kernel 1: coor = relu(x@W1^T)@W2^T -> bf16 [N,32] ----------------
__global__ __launch_bounds__(256) void coor_kernel(
    const float* __restrict__ x, const float* __restrict__ w1,
    const float* __restrict__ w2, unsigned short* __restrict__ coorb, int N)
{
    __shared__ float sW1[96];
    __shared__ float sW2[1024];
    const int tid = threadIdx.x;
    if (tid < 96) sW1[tid] = w1[tid];
    for (int i = tid; i < 1024; i += 256) sW2[i] = w2[i];
    __syncthreads();
    int n = blockIdx.x * 256 + tid;
    if (n >= N) return;
    const float x0 = x[n*3+0], x1 = x[n*3+1], x2 = x[n*3+2];
    float h[32];
#pragma unroll
    for (int k = 0; k < 32; ++k)
        h[k] = fmaxf(sW1[k*3+0]*x0 + sW1[k*3+1]*x1 + sW1[k*3+2]*x2, 0.0f);
    union { uint4 q[4]; unsigned u[16]; } st;
#pragma unroll
    for (int p = 0; p < 16; ++p) {
        float a0 = 0.f, a1 = 0.f;
#pragma unroll
        for (int k = 0; k < 32; ++k) {
            a0 += sW2[(2*p)  *32 + k] * h[k];
            a1 += sW2[(2*p+1)*32 + k] * h[k];
        }
        st.u[p] = pk2(a0, a1);
    }
    uint4* cp = (uint4*)(coorb + (size_t)n * 32);
#pragma unroll
    for (int w = 0; w < 4; ++w) cp[w] = st.q[w];
}

// ---------------- kernel 2: one-direction LSTM, 1 tile/wave, weights in LDS ----------------
// LDS (16KB, shared by 4 waves): wh frag [m*64+lane] at byte m*1024+lane*16; wx at +8192.
// Step skips (exact): t=0 no f-gate/no wh; t=7 no o-gate/no h.
template<int DIR>
__global__ __launch_bounds__(256, 4) void lstm_kernel(
    const float* __restrict__ edge_traj,
    const float* __restrict__ w_ih, const float* __restrict__ w_hh,
    const float* __restrict__ b_ih, const float* __restrict__ b_hh,
    unsigned* __restrict__ cbuf, int E)
{
    __shared__ unsigned lds_w[4096];
    const int tid = threadIdx.x;
    for (int i = tid; i < 512; i += 256) {
        const int m = i >> 6, ln = i & 63;
        const int le2 = ln & 15, lq2 = ln >> 4;
        const int row = 16*m + le2;
        const float s = (m == 4 || m == 5) ? LOG2E2 : -LOG2E;
        const float4 a = *(const float4*)(w_hh + row*32 + 4*lq2);
        const float4 b = *(const float4*)(w_hh + row*32 + 16 + 4*lq2);
        unsigned* wp = &lds_w[(size_t)i * 4];
        wp[0] = pk2(a.x*s, a.y*s); wp[1] = pk2(a.z*s, a.w*s);
        wp[2] = pk2(b.x*s, b.y*s); wp[3] = pk2(b.z*s, b.w*s);
        unsigned* xp = &lds_w[(size_t)(512 + i) * 4];
        if (lq2 == 0) {
            const float* p = w_ih + row * 6;
            xp[0] = pk2(p[0]*s, p[1]*s);
            xp[1] = pk2(p[2]*s, p[3]*s);
            xp[2] = pk2(p[4]*s, p[5]*s);
            xp[3] = pk2((b_ih[row] + b_hh[row])*s, 0.f);
        } else {
            xp[0] = 0u; xp[1] = 0u; xp[2] = 0u; xp[3] = 0u;
        }
    }
    __syncthreads();

    const int lane = tid & 63;
    const int wid  = tid >> 6;
    const int le   = lane & 15;
    const int lq   = lane >> 4;
    const bool l0  = (lq == 0);
    const unsigned lds_addr = (unsigned)(size_t)lds_w + (unsigned)lane * 16u;
    const f32x4 Z4 = {0.f, 0.f, 0.f, 0.f};

    const long tile = (long)blockIdx.x * 4 + wid;
    const long e0 = tile * 16;
    if (e0 >= E) return;
    const long er = e0 + le;
    const bool valid = er < E;
    const float* xb = edge_traj + (valid ? er : (E - 1)) * 48;

    U4 hf; hf.u[0]=hf.u[1]=hf.u[2]=hf.u[3]=0u;
    float cl[4]={0,0,0,0}, ch[4]={0,0,0,0};

#pragma unroll
    for (int t = 0; t < 8; ++t) {
        const int te = DIR ? (7 - t) : t;
        U4 xf;
        {
            const float* xp = xb + te * 6;
            const float2 a  = *(const float2*)xp;
            const float2 b2 = *(const float2*)(xp + 2);
            const float2 c2 = *(const float2*)(xp + 4);
            xf.u[0] = l0 ? pk2(a.x, a.y)   : 0u;
            xf.u[1] = l0 ? pk2(b2.x, b2.y) : 0u;
            xf.u[2] = l0 ? pk2(c2.x, c2.y) : 0u;
            xf.u[3] = l0 ? 0x3f80u         : 0u;
        }

        // ---- lo m-group {0,2,4,6}
        u32x4 f0,f1,f2,f3,f4,f5,f6,f7;
        LDS_RD8(f0,f1,f2,f3,f4,f5,f6,f7,
                "0","2048","4096","6144","8192","10240","12288","14336");
        f32x4 ai = MFMA(bc8(f4), xf.v, Z4, 0,0,0);
        f32x4 af = Z4, ao = Z4;
        if (t != 0) af = MFMA(bc8(f5), xf.v, Z4, 0,0,0);
        f32x4 ag = MFMA(bc8(f6), xf.v, Z4, 0,0,0);
        if (t != 7) ao = MFMA(bc8(f7), xf.v, Z4, 0,0,0);
        if (t > 0) {
            ai = MFMA(bc8(f0), hf.v, ai, 0,0,0);
            af = MFMA(bc8(f1), hf.v, af, 0,0,0);
            ag = MFMA(bc8(f2), hf.v, ag, 0,0,0);
            if (t != 7) ao = MFMA(bc8(f3), hf.v, ao, 0,0,0);
        }
        // hi m-group reads overlap lo MFMA latency
        u32x4 g0,g1,g2,g3,g4,g5,g6,g7;
        LDS_RD8(g0,g1,g2,g3,g4,g5,g6,g7,
                "1024","3072","5120","7168","9216","11264","13312","15360");

        float hl[4], hh[4];
        if (t == 0)      gates4_first(ai, ag, ao, cl, hl);
        else if (t == 7) gates4_last(ai, af, ag, cl);
        else             gates4_mid(ai, af, ag, ao, cl, hl);

        f32x4 bi = MFMA(bc8(g4), xf.v, Z4, 0,0,0);
        f32x4 bf = Z4, bo = Z4;
        if (t != 0) bf = MFMA(bc8(g5), xf.v, Z4, 0,0,0);
        f32x4 bg = MFMA(bc8(g6), xf.v, Z4, 0,0,0);
        if (t != 7) bo = MFMA(bc8(g7), xf.v, Z4, 0,0,0);
        if (t > 0) {
            bi = MFMA(bc8(g0), hf.v, bi, 0,0,0);
            bf = MFMA(bc8(g1), hf.v, bf, 0,0,0);
            bg = MFMA(bc8(g2), hf.v, bg, 0,0,0);
            if (t != 7) bo = MFMA(bc8(g3), hf.v, bo, 0,0,0);
        }
        if (t == 0)      gates4_first(bi, bg, bo, ch, hh);
        else if (t == 7) gates4_last(bi, bf, bg, ch);
        else             gates4_mid(bi, bf, bg, bo, ch, hh);

        if (t < 7) {
            hf.u[0] = pk2(hl[0], hl[1]); hf.u[1] = pk2(hl[2], hl[3]);
            hf.u[2] = pk2(hh[0], hh[1]); hf.u[3] = pk2(hh[2], hh[3]);
        }
    }

    // c -> sigma-layout e-major bf16
    if (valid) {
        U4 cw;
        cw.u[0] = pk2(cl[0], cl[1]);
        cw.u[1] = pk2(cl[2], cl[3]);
        cw.u[2] = pk2(ch[0], ch[1]);
        cw.u[3] = pk2(ch[2], ch[3]);
        unsigned* dp = cbuf + er * 16 + lq * 4;
        if (DIR == 0) {
            *(uint4*)dp = *(uint4*)cw.u;
        } else {
            const uint4 f = *(const uint4*)dp;
            uint4 o;
            o.x = pk2(0.5f*(lo2f(f.x)+lo2f(cw.u[0])), 0.5f*(hi2f(f.x)+hi2f(cw.u[0])));
            o.y = pk2(0.5f*(lo2f(f.y)+lo2f(cw.u[1])), 0.5f*(hi2f(f.y)+hi2f(cw.u[1])));
            o.z = pk2(0.5f*(lo2f(f.z)+lo2f(cw.u[2])), 0.5f*(hi2f(f.z)+hi2f(cw.u[2])));
            o.w = pk2(0.5f*(lo2f(f.w)+lo2f(cw.u[3])), 0.5f*(hi2f(f.w)+hi2f(cw.u[3])));
            *(uint4*)dp = o;
        }
    }
}

// ---------------- kernel 3: message MLP, writes msg bf16 IN PLACE over tr rows ----------------
__global__ __launch_bounds__(256, 4) void msg_kernel(
    unsigned* trmsg,
    const float* __restrict__ nn2_w1, const float* __restrict__ nn2_w2,
    const int* __restrict__ edge_index,
    const unsigned short* __restrict__ coorb, int E)
{
    const int lane = threadIdx.x & 63;
    const int wid  = threadIdx.x >> 6;
    const int le   = lane & 15;
    const int lq   = lane >> 4;
    const f32x4 Z4 = {0.f, 0.f, 0.f, 0.f};

    bf16x8 w1a[2][3], w2a[2];
#pragma unroll
    for (int mm = 0; mm < 2; ++mm) {
        const int row = 16*mm + le;
        w1a[mm][0] = ldw8(nn2_w1 + row*96 +  8*lq);
        w1a[mm][1] = ldw8(nn2_w1 + row*96 + 32 + 8*lq);
        w1a[mm][2] = ldw8p(nn2_w1 + row*96 + 64, lq, 1.0f);
        w2a[mm]    = ldw8p(nn2_w2 + row*32, lq, 1.0f);
    }

    const long gw = (long)blockIdx.x * 4 + wid;
    for (int it = 0; it < MTPW; ++it) {
        const long tile = gw * MTPW + it;
        const long e0 = tile * 16;
        if (e0 >= E) break;
        const long e_raw = e0 + le;
        const bool valid = e_raw < E;
        const long ec = valid ? e_raw : (E - 1);

        U4 tf;
        if (valid) *(uint4*)tf.u = *(const uint4*)(trmsg + e_raw * 16 + lq * 4);
        else tf.u[0] = tf.u[1] = tf.u[2] = tf.u[3] = 0u;

        const int src = edge_index[ec];
        const int dst = edge_index[E + ec];
        U4 df, sf;
        {
            const uint4 dv = *(const uint4*)(coorb + (size_t)dst*32 + lq*8);
            const uint4 sv = *(const uint4*)(coorb + (size_t)src*32 + lq*8);
            df.u[0]=dv.x; df.u[1]=dv.y; df.u[2]=dv.z; df.u[3]=dv.w;
            sf.u[0]=sv.x; sf.u[1]=sv.y; sf.u[2]=sv.z; sf.u[3]=sv.w;
        }

        f32x4 h1[2];
#pragma unroll
        for (int mm = 0; mm < 2; ++mm) {
            f32x4 a = MFMA(w1a[mm][0], df.v, Z4, 0,0,0);
            a = MFMA(w1a[mm][1], sf.v, a, 0,0,0);
            a = MFMA(w1a[mm][2], tf.v, a, 0,0,0);
            h1[mm] = a;
        }
        U4 gf;
        gf.u[0] = pk2(fmaxf(h1[0][0],0.f), fmaxf(h1[0][1],0.f));
        gf.u[1] = pk2(fmaxf(h1[0][2],0.f), fmaxf(h1[0][3],0.f));
        gf.u[2] = pk2(fmaxf(h1[1][0],0.f), fmaxf(h1[1][1],0.f));
        gf.u[3] = pk2(fmaxf(h1[1][2],0.f), fmaxf(h1[1][3],0.f));

        const f32x4 o0 = MFMA(w2a[0], gf.v, Z4, 0,0,0);
        const f32x4 o1 = MFMA(w2a[1], gf.v, Z4, 0,0,0);
        if (valid) {
            U4 cw;
            cw.u[0] = pk2(o0[0], o0[1]);
            cw.u[1] = pk2(o0[2], o0[3]);
            cw.u[2] = pk2(o1[0], o1[1]);
            cw.u[3] = pk2(o1[2], o1[3]);
            *(uint4*)(trmsg + e_raw * 16 + lq * 4) = *(uint4*)cw.u;
        }
    }
}

// ---------------- CSR build ----------------
__global__ __launch_bounds__(256) void hist_kernel(
    const int* __restrict__ ei, int* __restrict__ cnt, int E)
{
    const int e = blockIdx.x*256 + threadIdx.x;
    if (e < E) atomicAdd(&cnt[ei[E + e]], 1);
}

__global__ __launch_bounds__(256) void scan1_kernel(
    const int* __restrict__ cnt, int* __restrict__ bsum, int N)
{
    __shared__ int sp[4];
    const int tid = threadIdx.x;
    const int n = blockIdx.x*256 + tid;
    int c = (n < N) ? cnt[n] : 0;
#pragma unroll
    for (int m = 1; m < 64; m <<= 1) c += __shfl_xor(c, m, 64);
    if ((tid & 63) == 0) sp[tid >> 6] = c;
    __syncthreads();
    if (tid == 0) bsum[blockIdx.x] = sp[0] + sp[1] + sp[2] + sp[3];
}

__global__ __launch_bounds__(512) void scan2_kernel(
    int* __restrict__ bsum, int* __restrict__ offs, int nblk, int E, int N)
{
    __shared__ int s[512];
    const int tid = threadIdx.x;
    const int v = (tid < nblk) ? bsum[tid] : 0;
    s[tid] = v;
    __syncthreads();
    for (int off = 1; off < 512; off <<= 1) {
        const int t = (tid >= off) ? s[tid - off] : 0;
        __syncthreads();
        s[tid] += t;
        __syncthreads();
    }
    if (tid < nblk) bsum[tid] = s[tid] - v;
    if (tid == 0) offs[N] = E;
}

__global__ __launch_bounds__(256) void scan3_kernel(
    const int* __restrict__ cnt, const int* __restrict__ bsum,
    int* __restrict__ offs, int* __restrict__ cursor, int N)
{
    __shared__ int s[256];
    const int tid = threadIdx.x;
    const int n = blockIdx.x*256 + tid;
    const int v = (n < N) ? cnt[n] : 0;
    s[tid] = v;
    __syncthreads();
    for (int off = 1; off < 256; off <<= 1) {
        const int t = (tid >= off) ? s[tid - off] : 0;
        __syncthreads();
        s[tid] += t;
        __syncthreads();
    }
    if (n < N) {
        const int o = bsum[blockIdx.x] + s[tid] - v;
        offs[n] = o;
        cursor[n] = o;
    }
}

__global__ __launch_bounds__(256) void fill_kernel(
    const int* __restrict__ ei, int* __restrict__ cursor,
    int* __restrict__ eidx, int E)
{
    const int e = blockIdx.x*256 + threadIdx.x;
    if (e < E) {
        const int p = atomicAdd(&cursor[ei[E + e]], 1);
        eidx[p] = e;
    }
}

// ---------------- gather: aggv[n][slot] = sum of msg rows of incoming edges ----------------
__global__ __launch_bounds__(256) void gather_kernel(
    const unsigned* __restrict__ msg, const int* __restrict__ offs,
    const int* __restrict__ eidx, float* __restrict__ aggv, int N)
{
    const int lane = threadIdx.x & 63;
    const int wid  = threadIdx.x >> 6;
    const int g  = lane >> 4;
    const int le = lane & 15;
    const int n = blockIdx.x*16 + wid*4 + g;
    if (n >= N) return;
    const int beg = offs[n], end = offs[n+1];
    float sx = 0.f, sy = 0.f;
    for (int i = beg; i < end; ++i) {
        const unsigned w = msg[(size_t)eidx[i]*16 + le];
        sx += lo2f(w); sy += hi2f(w);
    }
    *(float2*)(aggv + (size_t)n*32 + 2*le) = float2{sx, sy};
}

// ---------------- agg: partials[b][k] = sum_{n in block} relu(aggv[n]@nn_w1^T)[k] ----------------
__global__ __launch_bounds__(256) void agg_kernel(
    const float* __restrict__ aggv, const float* __restrict__ nn_w1,
    float* __restrict__ partials, int N)
{
    __shared__ float sW[1024];
    __shared__ float sP[4][32];
    const int tid = threadIdx.x;
    for (int i = tid; i < 1024; i += 256) {
        const int jj = i >> 5, s = i & 31, q = s >> 3, j = s & 7;
        const int col = (j < 4) ? (4*q + j) : (16 + 4*q + (j - 4));
        sW[i] = nn_w1[jj*32 + col];
    }
    __syncthreads();
    const int n = blockIdx.x*256 + tid;
    float h[32];
    if (n < N) {
        float a[32];
        const float4* ap = (const float4*)(aggv + (size_t)n*32);
#pragma unroll
        for (int k4 = 0; k4 < 8; ++k4) {
            const float4 v = ap[k4];
            a[k4*4]=v.x; a[k4*4+1]=v.y; a[k4*4+2]=v.z; a[k4*4+3]=v.w;
        }
#pragma unroll
        for (int jj = 0; jj < 32; ++jj) {
            float acc = 0.f;
#pragma unroll
            for (int k = 0; k < 32; ++k) acc += sW[jj*32+k]*a[k];
            h[jj] = fmaxf(acc, 0.f);
        }
    } else {
#pragma unroll
        for (int jj = 0; jj < 32; ++jj) h[jj] = 0.f;
    }
#pragma unroll
    for (int m = 1; m < 64; m <<= 1) {
#pragma unroll
        for (int k = 0; k < 32; ++k) h[k] += __shfl_xor(h[k], m, 64);
    }
    if ((tid & 63) == 0) {
#pragma unroll
        for (int k = 0; k < 32; ++k) sP[tid >> 6][k] = h[k];
    }
    __syncthreads();
    if (tid < 32)
        partials[(size_t)blockIdx.x * 32 + tid]
            = sP[0][tid] + sP[1][tid] + sP[2][tid] + sP[3][tid];
}

// ---------------- final: s32 = sum(partials); out = nn_w2 @ s32 ----------------
__global__ __launch_bounds__(256) void reduce_kernel(
    const float* __restrict__ partials, const float* __restrict__ nn_w2,
    float* __restrict__ out, int nblk)
{
    __shared__ float sR[8][32];
    __shared__ float sS[32];
    const int tid = threadIdx.x;
    const int col = tid & 31;
    const int row = tid >> 5;
    float s = 0.f;
    for (int i = row; i < nblk; i += 8) s += partials[(size_t)i*32 + col];
    sR[row][col] = s;
    __syncthreads();
    if (row == 0) {
        float t = 0.f;
#pragma unroll
        for (int r = 0; r < 8; ++r) t += sR[r][col];
        sS[col] = t;
    }
    __syncthreads();
    if (tid < 64) {
        float acc = 0.f;
#pragma unroll
        for (int k = 0; k < 32; ++k) acc += nn_w2[tid*32+k] * sS[k];
        out[tid] = acc;
    }
}

extern "C" void kernel_launch(void* const* d_in, const int* in_sizes, int n_in,
                              void* d_out, int out_size, void* d_ws, size_t ws_size,
                              hipStream_t stream)
{
    const float* x         = (const float*)d_in[0];
    const float* edge_traj = (const float*)d_in[1];
    const float* w_ih_f    = (const float*)d_in[2];
    const float* w_hh_f    = (const float*)d_in[3];
    const float* b_ih_f    = (const float*)d_in[4];
    const float* b_hh_f    = (const float*)d_in[5];
    const float* w_ih_b    = (const float*)d_in[6];
    const float* w_hh_b    = (const float*)d_in[7];
    const float* b_ih_b    = (const float*)d_in[8];
    const float* b_hh_b    = (const float*)d_in[9];
    const float* coor_w1   = (const float*)d_in[10];
    const float* coor_w2   = (const float*)d_in[11];
    const float* nn2_w1    = (const float*)d_in[12];
    const float* nn2_w2    = (const float*)d_in[13];
    const float* nn_w1     = (const float*)d_in[14];
    const float* nn_w2     = (const float*)d_in[15];
    const int* edge_index  = (const int*)d_in[16];
    const int N = in_sizes[0] / 3;
    const int E = in_sizes[16] / 2;
    const int nblk = (N + 255) / 256;

    float* aggv = (float*)d_ws;                                   // N*32 f32
    float* partials = aggv + (size_t)N * 32;                      // nblk*32 f32
    unsigned short* coorb = (unsigned short*)(partials + (size_t)nblk * 32); // N*32 bf16
    unsigned* cbuf = (unsigned*)(coorb + (size_t)N * 32);         // E*16 u32
    int* cnt    = (int*)(cbuf + (size_t)E * 16);                  // N
    int* offs   = cnt + N;                                        // N+1
    int* cursor = offs + N + 1;                                   // N
    int* eidx   = cursor + N;                                     // E
    int* bsum   = eidx + E;                                       // nblk

    (void)hipMemsetAsync(cnt, 0, (size_t)N * sizeof(int), stream);

    coor_kernel<<<nblk, 256, 0, stream>>>(x, coor_w1, coor_w2, coorb, N);

    const long tiles   = ((long)E + 15) / 16;
    const int  lblocks = (int)((tiles + 3) / 4);
    lstm_kernel<0><<<lblocks, 256, 0, stream>>>(edge_traj,
        w_ih_f, w_hh_f, b_ih_f, b_hh_f, cbuf, E);
    lstm_kernel<1><<<lblocks, 256, 0, stream>>>(edge_traj,
        w_ih_b, w_hh_b, b_ih_b, b_hh_b, cbuf, E);

    const int eblk = (E + 255) / 256;
    hist_kernel<<<eblk, 256, 0, stream>>>(edge_index, cnt, E);
    scan1_kernel<<<nblk, 256, 0, stream>>>(cnt, bsum, N);
    scan2_kernel<<<1, 512, 0, stream>>>(bsum, offs, nblk, E, N);
    scan3_kernel<<<nblk, 256, 0, stream>>>(cnt, bsum, offs, cursor, N);
    fill_kernel<<<eblk, 256, 0, stream>>>(edge_index, cursor, eidx, E);

    const int mblocks = (int)((tiles + 4*MTPW - 1) / (4*MTPW));
    msg_kernel<<<mblocks, 256, 0, stream>>>(cbuf, nn2_w1, nn2_w2,
        edge_index, coorb, E);

    gather_kernel<<<(N + 15)/16, 256, 0, stream>>>(cbuf, offs, eidx, aggv, N);
    agg_kernel<<<nblk, 256, 0, stream>>>(aggv, nn_w1, partials, N);
    reduce_kernel<<<1, 256, 0, stream>>>(partials, nn_w2, (float*)d_out, nblk);
}